// Round 1
// baseline (8612.830 us; speedup 1.0000x reference)
//
#include <hip/hip_runtime.h>

// HetGTCN: 5-hop heterogeneous GNN on MI355X.
// Pipeline per call:
//   1. build CSR for 4 relations (hist -> scan -> scatter)   [edge lists fixed across hops]
//   2. fc1p/fc1a dense projections -> x_p/x_a (and h_p/h_a init)
//   3. 5 hops x 2 types: spmm2 (CSR gather) -> score (HAN sem-att) -> combine (softmax beta blend)
//   4. fc2 -> d_out [Np,64] f32

#define FEAT 128
#define SNODES 64
#define KLDS 120   // W1 rows staged in LDS (tail 8 rows in registers; 64KB static-LDS limit)

__global__ void zero_kernel(float* __restrict__ p, int n) {
  int i = blockIdx.x * blockDim.x + threadIdx.x;
  if (i < n) p[i] = 0.f;
}

__global__ void hist_kernel(const int* __restrict__ dst, int E, int* __restrict__ cnt) {
  int i = blockIdx.x * blockDim.x + threadIdx.x;
  if (i < E) atomicAdd(&cnt[dst[i]], 1);
}

// One block (1024 threads) per relation: chunked Hillis-Steele exclusive scan.
__global__ void scan4_kernel(const int* __restrict__ cnt, int* __restrict__ rp,
                             int* __restrict__ cur, int Np, int Na) {
  __shared__ int lds[1024];
  __shared__ int carry_s;
  int r = blockIdx.x;
  int N = (r < 2) ? Np : Na;
  size_t coff  = (r==0)?0 : (r==1)? (size_t)Np : (r==2)? (size_t)2*Np : (size_t)2*Np+Na;
  size_t rpoff = (r==0)?0 : (r==1)? (size_t)(Np+1) : (r==2)? (size_t)2*(Np+1) : (size_t)2*(Np+1)+(Na+1);
  const int* c = cnt + coff;
  int* rpp = rp + rpoff;
  int* cpp = cur + coff;
  int tid = threadIdx.x;
  if (tid == 0) carry_s = 0;
  __syncthreads();
  for (int base = 0; base < N; base += 1024) {
    int i = base + tid;
    int v = (i < N) ? c[i] : 0;
    lds[tid] = v;
    __syncthreads();
    for (int off = 1; off < 1024; off <<= 1) {
      int t = (tid >= off) ? lds[tid - off] : 0;
      __syncthreads();
      lds[tid] += t;
      __syncthreads();
    }
    int excl = lds[tid] - v;
    int carry = carry_s;
    if (i < N) { rpp[i] = carry + excl; cpp[i] = carry + excl; }
    __syncthreads();
    if (tid == 1023) carry_s = carry + lds[1023];
    __syncthreads();
  }
  if (tid == 0) rpp[N] = carry_s;
}

__global__ void scatter_kernel(const int* __restrict__ src, const int* __restrict__ dst,
                               const float* __restrict__ w, int* __restrict__ cur,
                               int* __restrict__ col, float* __restrict__ wout, int E) {
  int i = blockIdx.x * blockDim.x + threadIdx.x;
  if (i < E) {
    int p = atomicAdd(&cur[dst[i]], 1);
    col[p]  = src[i];
    wout[p] = w[i];
  }
}

// relu(x @ W + b), K in {256,128}, 128 outputs. Writes two copies (x_* and h_* init).
__global__ void fc1_kernel(const float* __restrict__ x, const float* __restrict__ W,
                           const float* __restrict__ b, float* __restrict__ o1,
                           float* __restrict__ o2, int K) {
  __shared__ float xs[256];
  int n = blockIdx.x, f = threadIdx.x;
  for (int t = f; t < K; t += 128) xs[t] = x[(size_t)n * K + t];
  __syncthreads();
  float acc = b[f];
  for (int k = 0; k < K; k++) acc = fmaf(xs[k], W[k * 128 + f], acc);
  acc = fmaxf(acc, 0.f);
  o1[(size_t)n * 128 + f] = acc;
  o2[(size_t)n * 128 + f] = acc;
}

// Per destination node: rel[n,0,:] = d0[n]*xself[n,:] + sum_e w0*h0[col0], same for rel 1.
__global__ void spmm2_kernel(const float* __restrict__ xself,
    const float* __restrict__ d0, const float* __restrict__ d1,
    const float* __restrict__ h0, const float* __restrict__ h1,
    const int* __restrict__ rp0, const int* __restrict__ col0, const float* __restrict__ w0,
    const int* __restrict__ rp1, const int* __restrict__ col1, const float* __restrict__ w1,
    float* __restrict__ rel) {
  int n = blockIdx.x, f = threadIdx.x;
  __shared__ int   ecol[128];
  __shared__ float ew[128];
  float xv = xself[(size_t)n * FEAT + f];
  float acc0 = d0[n] * xv;
  {
    int beg = rp0[n], end = rp0[n + 1];
    for (int cb = beg; cb < end; cb += 128) {
      int m = end - cb; if (m > 128) m = 128;
      __syncthreads();
      if (f < m) { ecol[f] = col0[cb + f]; ew[f] = w0[cb + f]; }
      __syncthreads();
      for (int e = 0; e < m; e++)
        acc0 = fmaf(ew[e], h0[(size_t)ecol[e] * FEAT + f], acc0);
    }
  }
  float acc1 = d1[n] * xv;
  {
    int beg = rp1[n], end = rp1[n + 1];
    for (int cb = beg; cb < end; cb += 128) {
      int m = end - cb; if (m > 128) m = 128;
      __syncthreads();
      if (f < m) { ecol[f] = col1[cb + f]; ew[f] = w1[cb + f]; }
      __syncthreads();
      for (int e = 0; e < m; e++)
        acc1 = fmaf(ew[e], h1[(size_t)ecol[e] * FEAT + f], acc1);
    }
  }
  rel[(size_t)n * 256 + f]       = acc0;
  rel[(size_t)n * 256 + 128 + f] = acc1;
}

// HAN semantic attention scores: s_out[r] += sum_n w2 . tanh(rel[n,r,:] @ W1 + b1)
// 256 threads: sub = tid>>7 selects relation, j = tid&127 the hidden column.
__global__ void score_kernel(const float* __restrict__ rel,
    const float* __restrict__ W1, const float* __restrict__ b1, const float* __restrict__ w2,
    float* __restrict__ s_out, int N) {
  __shared__ float w1s[KLDS * 128];
  __shared__ float rows[256];
  __shared__ float red[4];
  int tid = threadIdx.x;
  for (int t = tid; t < KLDS * 128; t += 256) w1s[t] = W1[t];
  int sub = tid >> 7, j = tid & 127;
  float w1r[8];
#pragma unroll
  for (int q = 0; q < 8; q++) w1r[q] = W1[(KLDS + q) * 128 + j];
  float b1v = b1[j], w2v = w2[j];
  __syncthreads();
  int n0 = blockIdx.x * SNODES;
  int n1 = n0 + SNODES; if (n1 > N) n1 = N;
  float pacc = 0.f;
  for (int n = n0; n < n1; n++) {
    __syncthreads();
    rows[tid] = rel[(size_t)n * 256 + tid];
    __syncthreads();
    const float* rw = &rows[sub * 128];
    float t = b1v;
#pragma unroll 8
    for (int k = 0; k < KLDS; k++) t = fmaf(rw[k], w1s[k * 128 + j], t);
#pragma unroll
    for (int q = 0; q < 8; q++) t = fmaf(rw[KLDS + q], w1r[q], t);
    pacc += w2v * tanhf(t);
  }
  float v = pacc;
#pragma unroll
  for (int m = 32; m >= 1; m >>= 1) v += __shfl_xor(v, m, 64);
  if ((tid & 63) == 0) red[tid >> 6] = v;
  __syncthreads();
  if (tid == 0)        atomicAdd(&s_out[0], red[0] + red[1]);
  else if (tid == 128) atomicAdd(&s_out[1], red[2] + red[3]);
}

// h[n,:] = beta0*rel[n,0,:] + beta1*rel[n,1,:], beta = softmax(s/N). float4 streaming.
__global__ void combine_kernel(const float4* __restrict__ rel4, const float* __restrict__ s,
                               float4* __restrict__ h4, int N, float invN) {
  int i = blockIdx.x * blockDim.x + threadIdx.x;
  if (i >= N * 32) return;
  float m0 = s[0] * invN, m1 = s[1] * invN;
  float mx = fmaxf(m0, m1);
  float e0 = expf(m0 - mx), e1 = expf(m1 - mx);
  float inv = 1.f / (e0 + e1);
  float be0 = e0 * inv, be1 = e1 * inv;
  int n = i >> 5, q = i & 31;
  float4 r0 = rel4[(size_t)n * 64 + q];
  float4 r1 = rel4[(size_t)n * 64 + 32 + q];
  float4 o;
  o.x = be0 * r0.x + be1 * r1.x;
  o.y = be0 * r0.y + be1 * r1.y;
  o.z = be0 * r0.z + be1 * r1.z;
  o.w = be0 * r0.w + be1 * r1.w;
  h4[(size_t)n * 32 + q] = o;
}

// out[n,:] = h[n,:] @ W(128x64) + b
__global__ void fc2_kernel(const float* __restrict__ h, const float* __restrict__ W,
                           const float* __restrict__ b, float* __restrict__ out) {
  __shared__ float hs[128];
  int n = blockIdx.x, j = threadIdx.x;  // 64 threads
  hs[j]      = h[(size_t)n * 128 + j];
  hs[j + 64] = h[(size_t)n * 128 + 64 + j];
  __syncthreads();
  float acc = b[j];
  for (int k = 0; k < 128; k++) acc = fmaf(hs[k], W[k * 64 + j], acc);
  out[(size_t)n * 64 + j] = acc;
}

extern "C" void kernel_launch(void* const* d_in, const int* in_sizes, int n_in,
                              void* d_out, int out_size, void* d_ws, size_t ws_size,
                              hipStream_t stream) {
  const float* x_paper  = (const float*)d_in[0];
  const float* x_author = (const float*)d_in[1];
  const float* fc1p_W = (const float*)d_in[2];
  const float* fc1p_b = (const float*)d_in[3];
  const float* fc1a_W = (const float*)d_in[4];
  const float* fc1a_b = (const float*)d_in[5];
  const float* fc2_W  = (const float*)d_in[6];
  const float* fc2_b  = (const float*)d_in[7];
  const float* semW1  = (const float*)d_in[8];
  const float* semb1  = (const float*)d_in[9];
  const float* semw2  = (const float*)d_in[10];
  const float* d_pp = (const float*)d_in[11];
  const float* d_pa = (const float*)d_in[12];
  const float* d_ap = (const float*)d_in[13];
  const float* d_aa = (const float*)d_in[14];
  const float* w_pp = (const float*)d_in[15];
  const float* w_pa = (const float*)d_in[16];
  const float* w_ap = (const float*)d_in[17];
  const float* w_aa = (const float*)d_in[18];
  const int* src_pp = (const int*)d_in[19];
  const int* dst_pp = (const int*)d_in[20];
  const int* src_pa = (const int*)d_in[21];
  const int* dst_pa = (const int*)d_in[22];
  const int* src_ap = (const int*)d_in[23];
  const int* dst_ap = (const int*)d_in[24];
  const int* src_aa = (const int*)d_in[25];
  const int* dst_aa = (const int*)d_in[26];

  const int Np = in_sizes[11];           // 100000
  const int Na = in_sizes[13];           // 100000
  const int Kp = in_sizes[0] / Np;       // 256
  const int Ka = in_sizes[1] / Na;       // 128
  const int E[4] = { in_sizes[15], in_sizes[16], in_sizes[17], in_sizes[18] };

  // workspace layout (float elements)
  float* ws = (float*)d_ws;
  size_t off = 0;
  float* xp  = ws + off; off += (size_t)Np * 128;
  float* xa  = ws + off; off += (size_t)Na * 128;
  float* hp  = ws + off; off += (size_t)Np * 128;
  float* ha  = ws + off; off += (size_t)Na * 128;
  float* rel = ws + off; off += (size_t)((Np > Na) ? Np : Na) * 256;
  float* ssum = ws + off; off += 32;                       // 20 used: [hop][type][r]
  int* cnt  = (int*)(ws + off); off += (size_t)2 * Np + 2 * Na;
  int* rpB  = (int*)(ws + off); off += (size_t)2 * (Np + 1) + 2 * (Na + 1);
  int* curB = (int*)(ws + off); off += (size_t)2 * Np + 2 * Na;
  size_t Esum = (size_t)E[0] + E[1] + E[2] + E[3];
  int* colB = (int*)(ws + off); off += Esum;
  float* wB = ws + off; off += Esum;
  (void)ws_size; (void)n_in; (void)out_size;

  int* cnt_r[4] = { cnt, cnt + Np, cnt + (size_t)2 * Np, cnt + (size_t)2 * Np + Na };
  int* rp_r[4]  = { rpB, rpB + (Np + 1), rpB + (size_t)2 * (Np + 1),
                    rpB + (size_t)2 * (Np + 1) + (Na + 1) };
  int* cur_r[4] = { curB, curB + Np, curB + (size_t)2 * Np, curB + (size_t)2 * Np + Na };
  size_t eoff[4] = { 0, (size_t)E[0], (size_t)E[0] + E[1], (size_t)E[0] + E[1] + E[2] };
  int* col_r[4]; float* w_r[4];
  for (int r = 0; r < 4; r++) { col_r[r] = colB + eoff[r]; w_r[r] = wB + eoff[r]; }

  const int* srcs[4]    = { src_pp, src_pa, src_ap, src_aa };
  const int* dsts[4]    = { dst_pp, dst_pa, dst_ap, dst_aa };
  const float* wedge[4] = { w_pp, w_pa, w_ap, w_aa };

  // 1. zero score slots + histogram counters
  int Z = 32 + 2 * Np + 2 * Na;
  zero_kernel<<<(Z + 255) / 256, 256, 0, stream>>>(ssum, Z);

  // 2. CSR build
  for (int r = 0; r < 4; r++)
    hist_kernel<<<(E[r] + 255) / 256, 256, 0, stream>>>(dsts[r], E[r], cnt_r[r]);
  scan4_kernel<<<4, 1024, 0, stream>>>(cnt, rpB, curB, Np, Na);
  for (int r = 0; r < 4; r++)
    scatter_kernel<<<(E[r] + 255) / 256, 256, 0, stream>>>(srcs[r], dsts[r], wedge[r],
                                                           cur_r[r], col_r[r], w_r[r], E[r]);

  // 3. input projections
  fc1_kernel<<<Np, 128, 0, stream>>>(x_paper, fc1p_W, fc1p_b, xp, hp, Kp);
  fc1_kernel<<<Na, 128, 0, stream>>>(x_author, fc1a_W, fc1a_b, xa, ha, Ka);

  // 4. hops
  for (int i = 0; i < 5; i++) {
    // paper: relations pp (gather h_p) and pa (gather h_a)
    float* sp = ssum + (size_t)(i * 2 + 0) * 2;
    spmm2_kernel<<<Np, 128, 0, stream>>>(xp, d_pp, d_pa, hp, ha,
        rp_r[0], col_r[0], w_r[0], rp_r[1], col_r[1], w_r[1], rel);
    score_kernel<<<(Np + SNODES - 1) / SNODES, 256, 0, stream>>>(rel,
        semW1 + (size_t)(i * 2 + 0) * 16384, semb1 + (size_t)(i * 2 + 0) * 128,
        semw2 + (size_t)(i * 2 + 0) * 128, sp, Np);
    combine_kernel<<<(Np * 32 + 255) / 256, 256, 0, stream>>>(
        (const float4*)rel, sp, (float4*)hp, Np, 1.f / Np);

    // author: relations ap (gather NEW h_p) and aa (gather h_a)
    float* sa = ssum + (size_t)(i * 2 + 1) * 2;
    spmm2_kernel<<<Na, 128, 0, stream>>>(xa, d_ap, d_aa, hp, ha,
        rp_r[2], col_r[2], w_r[2], rp_r[3], col_r[3], w_r[3], rel);
    score_kernel<<<(Na + SNODES - 1) / SNODES, 256, 0, stream>>>(rel,
        semW1 + (size_t)(i * 2 + 1) * 16384, semb1 + (size_t)(i * 2 + 1) * 128,
        semw2 + (size_t)(i * 2 + 1) * 128, sa, Na);
    combine_kernel<<<(Na * 32 + 255) / 256, 256, 0, stream>>>(
        (const float4*)rel, sa, (float4*)ha, Na, 1.f / Na);
  }

  // 5. output projection
  fc2_kernel<<<Np, 64, 0, stream>>>(hp, fc2_W, fc2_b, (float*)d_out);
}

// Round 2
// 4817.769 us; speedup vs baseline: 1.7877x; 1.7877x over previous
//
#include <hip/hip_runtime.h>

// HetGTCN: 5-hop heterogeneous GNN on MI355X.
//   1. CSR build for 4 relations (hist -> scan -> scatter)
//   2. fc1p/fc1a register-blocked dense projections
//   3. 5 hops x 2 types: spmm2 (wave-per-node float4 gather) -> score (bf16 MFMA, W1 in regs)
//      -> combine (softmax beta blend)
//   4. fc2 -> d_out [Np,64] f32

#define FEAT 128

typedef __attribute__((ext_vector_type(8))) short bf16x8;
typedef __attribute__((ext_vector_type(4))) float f32x4;

__device__ inline short f2bf(float f) {
  union { float f; unsigned u; } x; x.f = f;
  unsigned r = x.u + 0x7fff + ((x.u >> 16) & 1);   // RNE
  return (short)(r >> 16);
}

__global__ void zero_kernel(float* __restrict__ p, int n) {
  int i = blockIdx.x * blockDim.x + threadIdx.x;
  if (i < n) p[i] = 0.f;
}

__global__ void hist_kernel(const int* __restrict__ dst, int E, int* __restrict__ cnt) {
  int i = blockIdx.x * blockDim.x + threadIdx.x;
  if (i < E) atomicAdd(&cnt[dst[i]], 1);
}

// One block (1024 threads) per relation: chunked Hillis-Steele exclusive scan.
__global__ void scan4_kernel(const int* __restrict__ cnt, int* __restrict__ rp,
                             int* __restrict__ cur, int Np, int Na) {
  __shared__ int lds[1024];
  __shared__ int carry_s;
  int r = blockIdx.x;
  int N = (r < 2) ? Np : Na;
  size_t coff  = (r==0)?0 : (r==1)? (size_t)Np : (r==2)? (size_t)2*Np : (size_t)2*Np+Na;
  size_t rpoff = (r==0)?0 : (r==1)? (size_t)(Np+1) : (r==2)? (size_t)2*(Np+1) : (size_t)2*(Np+1)+(Na+1);
  const int* c = cnt + coff;
  int* rpp = rp + rpoff;
  int* cpp = cur + coff;
  int tid = threadIdx.x;
  if (tid == 0) carry_s = 0;
  __syncthreads();
  for (int base = 0; base < N; base += 1024) {
    int i = base + tid;
    int v = (i < N) ? c[i] : 0;
    lds[tid] = v;
    __syncthreads();
    for (int off = 1; off < 1024; off <<= 1) {
      int t = (tid >= off) ? lds[tid - off] : 0;
      __syncthreads();
      lds[tid] += t;
      __syncthreads();
    }
    int excl = lds[tid] - v;
    int carry = carry_s;
    if (i < N) { rpp[i] = carry + excl; cpp[i] = carry + excl; }
    __syncthreads();
    if (tid == 1023) carry_s = carry + lds[1023];
    __syncthreads();
  }
  if (tid == 0) rpp[N] = carry_s;
}

__global__ void scatter_kernel(const int* __restrict__ src, const int* __restrict__ dst,
                               const float* __restrict__ w, int* __restrict__ cur,
                               int* __restrict__ col, float* __restrict__ wout, int E) {
  int i = blockIdx.x * blockDim.x + threadIdx.x;
  if (i < E) {
    int p = atomicAdd(&cur[dst[i]], 1);
    col[p]  = src[i];
    wout[p] = w[i];
  }
}

// relu(x @ W + b): 16 nodes x 128 feats per block, 256 threads, 8 acc/thread.
template<int K>
__global__ __launch_bounds__(256) void fc1_kernel(const float* __restrict__ x,
    const float* __restrict__ W, const float* __restrict__ b,
    float* __restrict__ o1, float* __restrict__ o2, int N) {
  __shared__ float xs[16][K + 4];
  int tid = threadIdx.x;
  int f = tid & 127, g = tid >> 7;          // g in {0,1}: node-halves
  int n0 = blockIdx.x * 16;
  for (int idx = tid; idx < 16 * K; idx += 256) {
    int node = idx >> (K == 256 ? 8 : 7);
    int k = idx & (K - 1);
    int n = n0 + node;
    xs[node][k] = (n < N) ? x[(size_t)n * K + k] : 0.f;
  }
  __syncthreads();
  float acc[8];
  float bv = b[f];
#pragma unroll
  for (int rr = 0; rr < 8; rr++) acc[rr] = bv;
  for (int k = 0; k < K; k += 4) {
    float w0 = W[(size_t)k * 128 + f];
    float w1 = W[(size_t)(k + 1) * 128 + f];
    float w2 = W[(size_t)(k + 2) * 128 + f];
    float w3 = W[(size_t)(k + 3) * 128 + f];
#pragma unroll
    for (int rr = 0; rr < 8; rr++) {
      float4 xv = *(const float4*)&xs[g * 8 + rr][k];
      acc[rr] = fmaf(xv.x, w0, acc[rr]);
      acc[rr] = fmaf(xv.y, w1, acc[rr]);
      acc[rr] = fmaf(xv.z, w2, acc[rr]);
      acc[rr] = fmaf(xv.w, w3, acc[rr]);
    }
  }
#pragma unroll
  for (int rr = 0; rr < 8; rr++) {
    int n = n0 + g * 8 + rr;
    if (n < N) {
      float v = fmaxf(acc[rr], 0.f);
      o1[(size_t)n * 128 + f] = v;
      o2[(size_t)n * 128 + f] = v;
    }
  }
}

// Wave-per-node SPMM over 2 relations. float4 gathers, 2 edges per iteration.
__global__ __launch_bounds__(256) void spmm2_kernel(
    const float4* __restrict__ xself4,
    const float* __restrict__ d0, const float* __restrict__ d1,
    const float4* __restrict__ h0, const float4* __restrict__ h1,
    const int* __restrict__ rp0, const int* __restrict__ col0, const float* __restrict__ w0,
    const int* __restrict__ rp1, const int* __restrict__ col1, const float* __restrict__ w1,
    float4* __restrict__ rel4, int N) {
  int tid = threadIdx.x;
  int lane = tid & 63, wid = tid >> 6;
  int q = lane & 31, eo = lane >> 5;
  int n = blockIdx.x * 4 + wid;
  if (n >= N) return;
  float4 xv = xself4[(size_t)n * 32 + q];
#pragma unroll
  for (int srel = 0; srel < 2; srel++) {
    const float sd = srel ? d1[n] : d0[n];
    const int* rp = srel ? rp1 : rp0;
    const int* col = srel ? col1 : col0;
    const float* wv_arr = srel ? w1 : w0;
    const float4* h = srel ? h1 : h0;
    float4 acc;
    acc.x = eo ? 0.f : sd * xv.x;
    acc.y = eo ? 0.f : sd * xv.y;
    acc.z = eo ? 0.f : sd * xv.z;
    acc.w = eo ? 0.f : sd * xv.w;
    int beg = rp[n], end = rp[n + 1];
    for (int cb = beg; cb < end; cb += 64) {
      int m = end - cb; if (m > 64) m = 64;
      int creg = 0; float wreg = 0.f;
      if (lane < m) { creg = col[cb + lane]; wreg = wv_arr[cb + lane]; }
      int half = m >> 1;
      for (int i = 0; i < half; i++) {
        int e = 2 * i + eo;
        int c = __shfl(creg, e);
        float wv = __shfl(wreg, e);
        float4 hv = h[(size_t)c * 32 + q];
        acc.x = fmaf(wv, hv.x, acc.x);
        acc.y = fmaf(wv, hv.y, acc.y);
        acc.z = fmaf(wv, hv.z, acc.z);
        acc.w = fmaf(wv, hv.w, acc.w);
      }
      if (m & 1) {
        int c = __shfl(creg, m - 1);
        float wv = __shfl(wreg, m - 1);
        if (eo == 0) {
          float4 hv = h[(size_t)c * 32 + q];
          acc.x = fmaf(wv, hv.x, acc.x);
          acc.y = fmaf(wv, hv.y, acc.y);
          acc.z = fmaf(wv, hv.z, acc.z);
          acc.w = fmaf(wv, hv.w, acc.w);
        }
      }
    }
    acc.x += __shfl_xor(acc.x, 32);
    acc.y += __shfl_xor(acc.y, 32);
    acc.z += __shfl_xor(acc.z, 32);
    acc.w += __shfl_xor(acc.w, 32);
    if (eo == 0) rel4[(size_t)n * 64 + srel * 32 + q] = acc;
  }
}

// HAN scores via bf16 MFMA. W1 held in registers as B-frags, reused across node tiles.
// s_out[r] += sum_n w2 . tanh(rel[n,r,:] @ W1 + b1)
__global__ __launch_bounds__(256) void score_mfma_kernel(
    const float* __restrict__ rel,      // [N,2,128]
    const float* __restrict__ W1,       // [128,128] (k-major)
    const float* __restrict__ b1, const float* __restrict__ w2,
    float* __restrict__ s_out, int N, int nwaves) {
  int tid = threadIdx.x;
  int lane = tid & 63;
  int gw = blockIdx.x * 4 + (tid >> 6);
  int r = lane & 15;       // A-row / B-col / C-col
  int kg = lane >> 4;      // k-group: k = kt*32 + kg*8 + t
  // B fragments: full W1, 8 j-tiles x 4 k-tiles
  bf16x8 bfr[8][4];
#pragma unroll
  for (int jt = 0; jt < 8; jt++) {
    int j = jt * 16 + r;
#pragma unroll
    for (int kt = 0; kt < 4; kt++) {
      int k0 = kt * 32 + kg * 8;
      bf16x8 v;
#pragma unroll
      for (int t = 0; t < 8; t++) v[t] = f2bf(W1[(size_t)(k0 + t) * 128 + j]);
      bfr[jt][kt] = v;
    }
  }
  float b1v[8], w2v[8];
#pragma unroll
  for (int jt = 0; jt < 8; jt++) { b1v[jt] = b1[jt * 16 + r]; w2v[jt] = w2[jt * 16 + r]; }
  float s0 = 0.f, s1 = 0.f;
  int ntiles = (N + 15) >> 4;
  for (int tile = gw; tile < ntiles; tile += nwaves) {
    int n0 = tile * 16;
    int nodeA = n0 + r;
    size_t base = (size_t)((nodeA < N) ? nodeA : 0) * 256;
#pragma unroll
    for (int sub = 0; sub < 2; sub++) {
      bf16x8 afr[4];
#pragma unroll
      for (int kt = 0; kt < 4; kt++) {
        const float4* p = (const float4*)(rel + base + sub * 128 + kt * 32 + kg * 8);
        float4 lo = p[0], hi = p[1];
        bf16x8 v;
        v[0] = f2bf(lo.x); v[1] = f2bf(lo.y); v[2] = f2bf(lo.z); v[3] = f2bf(lo.w);
        v[4] = f2bf(hi.x); v[5] = f2bf(hi.y); v[6] = f2bf(hi.z); v[7] = f2bf(hi.w);
        afr[kt] = v;
      }
      f32x4 acc[8];
#pragma unroll
      for (int jt = 0; jt < 8; jt++) acc[jt] = (f32x4){0.f, 0.f, 0.f, 0.f};
#pragma unroll
      for (int jt = 0; jt < 8; jt++)
#pragma unroll
        for (int kt = 0; kt < 4; kt++)
          acc[jt] = __builtin_amdgcn_mfma_f32_16x16x32_bf16(afr[kt], bfr[jt][kt], acc[jt], 0, 0, 0);
      // C layout: col = lane&15 (=j within tile), row = kg*4 + reg (= node within tile)
      float sacc = 0.f;
#pragma unroll
      for (int jt = 0; jt < 8; jt++) {
#pragma unroll
        for (int reg = 0; reg < 4; reg++) {
          int nm = n0 + kg * 4 + reg;
          if (nm < N) sacc += w2v[jt] * tanhf(acc[jt][reg] + b1v[jt]);
        }
      }
      if (sub == 0) s0 += sacc; else s1 += sacc;
    }
  }
#pragma unroll
  for (int m = 32; m >= 1; m >>= 1) { s0 += __shfl_xor(s0, m); s1 += __shfl_xor(s1, m); }
  if (lane == 0) { atomicAdd(&s_out[0], s0); atomicAdd(&s_out[1], s1); }
}

// h[n,:] = beta0*rel[n,0,:] + beta1*rel[n,1,:], beta = softmax(s/N).
__global__ void combine_kernel(const float4* __restrict__ rel4, const float* __restrict__ s,
                               float4* __restrict__ h4, int N, float invN) {
  int i = blockIdx.x * blockDim.x + threadIdx.x;
  if (i >= N * 32) return;
  float m0 = s[0] * invN, m1 = s[1] * invN;
  float mx = fmaxf(m0, m1);
  float e0 = expf(m0 - mx), e1 = expf(m1 - mx);
  float inv = 1.f / (e0 + e1);
  float be0 = e0 * inv, be1 = e1 * inv;
  int n = i >> 5, q = i & 31;
  float4 r0 = rel4[(size_t)n * 64 + q];
  float4 r1 = rel4[(size_t)n * 64 + 32 + q];
  float4 o;
  o.x = be0 * r0.x + be1 * r1.x;
  o.y = be0 * r0.y + be1 * r1.y;
  o.z = be0 * r0.z + be1 * r1.z;
  o.w = be0 * r0.w + be1 * r1.w;
  h4[(size_t)n * 32 + q] = o;
}

// out[n,:] = h[n,:] @ W(128x64) + b
__global__ void fc2_kernel(const float* __restrict__ h, const float* __restrict__ W,
                           const float* __restrict__ b, float* __restrict__ out) {
  __shared__ float hs[128];
  int n = blockIdx.x, j = threadIdx.x;  // 64 threads
  hs[j]      = h[(size_t)n * 128 + j];
  hs[j + 64] = h[(size_t)n * 128 + 64 + j];
  __syncthreads();
  float acc = b[j];
  for (int k = 0; k < 128; k++) acc = fmaf(hs[k], W[k * 64 + j], acc);
  out[(size_t)n * 64 + j] = acc;
}

extern "C" void kernel_launch(void* const* d_in, const int* in_sizes, int n_in,
                              void* d_out, int out_size, void* d_ws, size_t ws_size,
                              hipStream_t stream) {
  const float* x_paper  = (const float*)d_in[0];
  const float* x_author = (const float*)d_in[1];
  const float* fc1p_W = (const float*)d_in[2];
  const float* fc1p_b = (const float*)d_in[3];
  const float* fc1a_W = (const float*)d_in[4];
  const float* fc1a_b = (const float*)d_in[5];
  const float* fc2_W  = (const float*)d_in[6];
  const float* fc2_b  = (const float*)d_in[7];
  const float* semW1  = (const float*)d_in[8];
  const float* semb1  = (const float*)d_in[9];
  const float* semw2  = (const float*)d_in[10];
  const float* d_pp = (const float*)d_in[11];
  const float* d_pa = (const float*)d_in[12];
  const float* d_ap = (const float*)d_in[13];
  const float* d_aa = (const float*)d_in[14];
  const float* w_pp = (const float*)d_in[15];
  const float* w_pa = (const float*)d_in[16];
  const float* w_ap = (const float*)d_in[17];
  const float* w_aa = (const float*)d_in[18];
  const int* src_pp = (const int*)d_in[19];
  const int* dst_pp = (const int*)d_in[20];
  const int* src_pa = (const int*)d_in[21];
  const int* dst_pa = (const int*)d_in[22];
  const int* src_ap = (const int*)d_in[23];
  const int* dst_ap = (const int*)d_in[24];
  const int* src_aa = (const int*)d_in[25];
  const int* dst_aa = (const int*)d_in[26];

  const int Np = in_sizes[11];
  const int Na = in_sizes[13];
  const int E[4] = { in_sizes[15], in_sizes[16], in_sizes[17], in_sizes[18] };

  float* ws = (float*)d_ws;
  size_t off = 0;
  float* xp  = ws + off; off += (size_t)Np * 128;
  float* xa  = ws + off; off += (size_t)Na * 128;
  float* hp  = ws + off; off += (size_t)Np * 128;
  float* ha  = ws + off; off += (size_t)Na * 128;
  float* rel = ws + off; off += (size_t)((Np > Na) ? Np : Na) * 256;
  float* ssum = ws + off; off += 32;
  int* cnt  = (int*)(ws + off); off += (size_t)2 * Np + 2 * Na;
  int* rpB  = (int*)(ws + off); off += (size_t)2 * (Np + 1) + 2 * (Na + 1);
  int* curB = (int*)(ws + off); off += (size_t)2 * Np + 2 * Na;
  size_t Esum = (size_t)E[0] + E[1] + E[2] + E[3];
  int* colB = (int*)(ws + off); off += Esum;
  float* wB = ws + off; off += Esum;
  (void)ws_size; (void)n_in; (void)out_size;

  int* cnt_r[4] = { cnt, cnt + Np, cnt + (size_t)2 * Np, cnt + (size_t)2 * Np + Na };
  int* rp_r[4]  = { rpB, rpB + (Np + 1), rpB + (size_t)2 * (Np + 1),
                    rpB + (size_t)2 * (Np + 1) + (Na + 1) };
  int* cur_r[4] = { curB, curB + Np, curB + (size_t)2 * Np, curB + (size_t)2 * Np + Na };
  size_t eoff[4] = { 0, (size_t)E[0], (size_t)E[0] + E[1], (size_t)E[0] + E[1] + E[2] };
  int* col_r[4]; float* w_r[4];
  for (int r = 0; r < 4; r++) { col_r[r] = colB + eoff[r]; w_r[r] = wB + eoff[r]; }

  const int* srcs[4]    = { src_pp, src_pa, src_ap, src_aa };
  const int* dsts[4]    = { dst_pp, dst_pa, dst_ap, dst_aa };
  const float* wedge[4] = { w_pp, w_pa, w_ap, w_aa };

  int Z = 32 + 2 * Np + 2 * Na;
  zero_kernel<<<(Z + 255) / 256, 256, 0, stream>>>(ssum, Z);

  for (int r = 0; r < 4; r++)
    hist_kernel<<<(E[r] + 255) / 256, 256, 0, stream>>>(dsts[r], E[r], cnt_r[r]);
  scan4_kernel<<<4, 1024, 0, stream>>>(cnt, rpB, curB, Np, Na);
  for (int r = 0; r < 4; r++)
    scatter_kernel<<<(E[r] + 255) / 256, 256, 0, stream>>>(srcs[r], dsts[r], wedge[r],
                                                           cur_r[r], col_r[r], w_r[r], E[r]);

  fc1_kernel<256><<<(Np + 15) / 16, 256, 0, stream>>>(x_paper, fc1p_W, fc1p_b, xp, hp, Np);
  fc1_kernel<128><<<(Na + 15) / 16, 256, 0, stream>>>(x_author, fc1a_W, fc1a_b, xa, ha, Na);

  const int SCORE_BLOCKS = 128;
  const int SCORE_WAVES = SCORE_BLOCKS * 4;

  for (int i = 0; i < 5; i++) {
    // paper: pp (gather h_p), pa (gather h_a)
    float* sp = ssum + (size_t)(i * 2 + 0) * 2;
    spmm2_kernel<<<(Np + 3) / 4, 256, 0, stream>>>((const float4*)xp, d_pp, d_pa,
        (const float4*)hp, (const float4*)ha,
        rp_r[0], col_r[0], w_r[0], rp_r[1], col_r[1], w_r[1], (float4*)rel, Np);
    score_mfma_kernel<<<SCORE_BLOCKS, 256, 0, stream>>>(rel,
        semW1 + (size_t)(i * 2 + 0) * 16384, semb1 + (size_t)(i * 2 + 0) * 128,
        semw2 + (size_t)(i * 2 + 0) * 128, sp, Np, SCORE_WAVES);
    combine_kernel<<<(Np * 32 + 255) / 256, 256, 0, stream>>>(
        (const float4*)rel, sp, (float4*)hp, Np, 1.f / Np);

    // author: ap (gather new h_p), aa (gather h_a)
    float* sa = ssum + (size_t)(i * 2 + 1) * 2;
    spmm2_kernel<<<(Na + 3) / 4, 256, 0, stream>>>((const float4*)xa, d_ap, d_aa,
        (const float4*)hp, (const float4*)ha,
        rp_r[2], col_r[2], w_r[2], rp_r[3], col_r[3], w_r[3], (float4*)rel, Na);
    score_mfma_kernel<<<SCORE_BLOCKS, 256, 0, stream>>>(rel,
        semW1 + (size_t)(i * 2 + 1) * 16384, semb1 + (size_t)(i * 2 + 1) * 128,
        semw2 + (size_t)(i * 2 + 1) * 128, sa, Na, SCORE_WAVES);
    combine_kernel<<<(Na * 32 + 255) / 256, 256, 0, stream>>>(
        (const float4*)rel, sa, (float4*)ha, Na, 1.f / Na);
  }

  fc2_kernel<<<Np, 64, 0, stream>>>(hp, fc2_W, fc2_b, (float*)d_out);
}

// Round 3
// 3390.516 us; speedup vs baseline: 2.5403x; 1.4210x over previous
//
#include <hip/hip_runtime.h>

// HetGTCN: 5-hop heterogeneous GNN on MI355X.
//   1. CSR build for 4 relations (hist -> scan -> scatter)
//   2. fc1p/fc1a register-blocked dense projections -> bf16 x/h tables
//   3. 5 hops x 2 types: spmm2 (bf16 gather, 4 edges/wave-issue) -> score (bf16 MFMA)
//      -> combine (softmax beta blend, bf16)
//   4. fc2 -> d_out [Np,64] f32
// bf16 is used for all gather/stream tensors (h, x, rel): halves the random-gather
// HBM traffic that dominates (round-2 profile: spmm2 FETCH 819MB @49% HBM peak).

typedef __attribute__((ext_vector_type(8))) short bf16x8;
typedef __attribute__((ext_vector_type(4))) float f32x4;
typedef unsigned short ushort_t;

__device__ inline unsigned short f2bf(float f) {
  union { float f; unsigned u; } x; x.f = f;
  unsigned r = x.u + 0x7fff + ((x.u >> 16) & 1);   // RNE
  return (unsigned short)(r >> 16);
}
__device__ inline float bf2f(unsigned short u) {
  union { unsigned u; float f; } x; x.u = (unsigned)u << 16; return x.f;
}
__device__ inline void unpack8(uint4 u, float* f) {
  union { unsigned u; float f; } c;
  c.u = u.x << 16;          f[0] = c.f;
  c.u = u.x & 0xffff0000u;  f[1] = c.f;
  c.u = u.y << 16;          f[2] = c.f;
  c.u = u.y & 0xffff0000u;  f[3] = c.f;
  c.u = u.z << 16;          f[4] = c.f;
  c.u = u.z & 0xffff0000u;  f[5] = c.f;
  c.u = u.w << 16;          f[6] = c.f;
  c.u = u.w & 0xffff0000u;  f[7] = c.f;
}
__device__ inline uint4 pack8(const float* f) {
  uint4 u;
  u.x = (unsigned)f2bf(f[0]) | ((unsigned)f2bf(f[1]) << 16);
  u.y = (unsigned)f2bf(f[2]) | ((unsigned)f2bf(f[3]) << 16);
  u.z = (unsigned)f2bf(f[4]) | ((unsigned)f2bf(f[5]) << 16);
  u.w = (unsigned)f2bf(f[6]) | ((unsigned)f2bf(f[7]) << 16);
  return u;
}

__global__ void zero_kernel(float* __restrict__ p, int n) {
  int i = blockIdx.x * blockDim.x + threadIdx.x;
  if (i < n) p[i] = 0.f;
}

__global__ void hist_kernel(const int* __restrict__ dst, int E, int* __restrict__ cnt) {
  int i = blockIdx.x * blockDim.x + threadIdx.x;
  if (i < E) atomicAdd(&cnt[dst[i]], 1);
}

// One block (1024 threads) per relation: chunked Hillis-Steele exclusive scan.
__global__ void scan4_kernel(const int* __restrict__ cnt, int* __restrict__ rp,
                             int* __restrict__ cur, int Np, int Na) {
  __shared__ int lds[1024];
  __shared__ int carry_s;
  int r = blockIdx.x;
  int N = (r < 2) ? Np : Na;
  size_t coff  = (r==0)?0 : (r==1)? (size_t)Np : (r==2)? (size_t)2*Np : (size_t)2*Np+Na;
  size_t rpoff = (r==0)?0 : (r==1)? (size_t)(Np+1) : (r==2)? (size_t)2*(Np+1) : (size_t)2*(Np+1)+(Na+1);
  const int* c = cnt + coff;
  int* rpp = rp + rpoff;
  int* cpp = cur + coff;
  int tid = threadIdx.x;
  if (tid == 0) carry_s = 0;
  __syncthreads();
  for (int base = 0; base < N; base += 1024) {
    int i = base + tid;
    int v = (i < N) ? c[i] : 0;
    lds[tid] = v;
    __syncthreads();
    for (int off = 1; off < 1024; off <<= 1) {
      int t = (tid >= off) ? lds[tid - off] : 0;
      __syncthreads();
      lds[tid] += t;
      __syncthreads();
    }
    int excl = lds[tid] - v;
    int carry = carry_s;
    if (i < N) { rpp[i] = carry + excl; cpp[i] = carry + excl; }
    __syncthreads();
    if (tid == 1023) carry_s = carry + lds[1023];
    __syncthreads();
  }
  if (tid == 0) rpp[N] = carry_s;
}

__global__ void scatter_kernel(const int* __restrict__ src, const int* __restrict__ dst,
                               const float* __restrict__ w, int* __restrict__ cur,
                               int* __restrict__ col, float* __restrict__ wout, int E) {
  int i = blockIdx.x * blockDim.x + threadIdx.x;
  if (i < E) {
    int p = atomicAdd(&cur[dst[i]], 1);
    col[p]  = src[i];
    wout[p] = w[i];
  }
}

// relu(x @ W + b): 16 nodes x 128 feats per block, 256 threads, 8 acc/thread.
// Outputs bf16 copies: o1 = x table, o2 = h table.
template<int K>
__global__ __launch_bounds__(256) void fc1_kernel(const float* __restrict__ x,
    const float* __restrict__ W, const float* __restrict__ b,
    ushort_t* __restrict__ o1, ushort_t* __restrict__ o2, int N) {
  __shared__ float xs[16][K + 4];
  int tid = threadIdx.x;
  int f = tid & 127, g = tid >> 7;
  int n0 = blockIdx.x * 16;
  for (int idx = tid; idx < 16 * K; idx += 256) {
    int node = idx >> (K == 256 ? 8 : 7);
    int k = idx & (K - 1);
    int n = n0 + node;
    xs[node][k] = (n < N) ? x[(size_t)n * K + k] : 0.f;
  }
  __syncthreads();
  float acc[8];
  float bv = b[f];
#pragma unroll
  for (int rr = 0; rr < 8; rr++) acc[rr] = bv;
  for (int k = 0; k < K; k += 4) {
    float w0 = W[(size_t)k * 128 + f];
    float w1 = W[(size_t)(k + 1) * 128 + f];
    float w2 = W[(size_t)(k + 2) * 128 + f];
    float w3 = W[(size_t)(k + 3) * 128 + f];
#pragma unroll
    for (int rr = 0; rr < 8; rr++) {
      float4 xv = *(const float4*)&xs[g * 8 + rr][k];
      acc[rr] = fmaf(xv.x, w0, acc[rr]);
      acc[rr] = fmaf(xv.y, w1, acc[rr]);
      acc[rr] = fmaf(xv.z, w2, acc[rr]);
      acc[rr] = fmaf(xv.w, w3, acc[rr]);
    }
  }
#pragma unroll
  for (int rr = 0; rr < 8; rr++) {
    int n = n0 + g * 8 + rr;
    if (n < N) {
      unsigned short v = f2bf(fmaxf(acc[rr], 0.f));
      o1[(size_t)n * 128 + f] = v;
      o2[(size_t)n * 128 + f] = v;
    }
  }
}

// Wave-per-node SPMM over 2 relations, bf16 rows (256B): 16 lanes x 16B per row,
// 4 edges per wave-issue (eslot = lane>>4), 2-quad unrolled for MLP.
__global__ __launch_bounds__(256) void spmm2_kernel(
    const ushort_t* __restrict__ xself,
    const float* __restrict__ d0, const float* __restrict__ d1,
    const ushort_t* __restrict__ h0, const ushort_t* __restrict__ h1,
    const int* __restrict__ rp0, const int* __restrict__ col0, const float* __restrict__ w0,
    const int* __restrict__ rp1, const int* __restrict__ col1, const float* __restrict__ w1,
    ushort_t* __restrict__ rel, int N) {
  int tid = threadIdx.x;
  int lane = tid & 63, wid = tid >> 6;
  int fg = lane & 15;       // feature group: features fg*8 .. fg*8+7
  int eslot = lane >> 4;    // 0..3
  int n = blockIdx.x * 4 + wid;
  if (n >= N) return;
  float xf[8];
  unpack8(*(const uint4*)(xself + (size_t)n * 128 + fg * 8), xf);
#pragma unroll
  for (int srel = 0; srel < 2; srel++) {
    const float sd = srel ? d1[n] : d0[n];
    const int* rp = srel ? rp1 : rp0;
    const int* col = srel ? col1 : col0;
    const float* wv_arr = srel ? w1 : w0;
    const ushort_t* h = srel ? h1 : h0;
    float acc[8];
#pragma unroll
    for (int t = 0; t < 8; t++) acc[t] = 0.f;
    int beg = rp[n], end = rp[n + 1];
    for (int cb = beg; cb < end; cb += 64) {
      int m = end - cb; if (m > 64) m = 64;
      int creg = 0; float wreg = 0.f;
      if (lane < m) { creg = col[cb + lane]; wreg = wv_arr[cb + lane]; }
      for (int i = 0; i < m; i += 8) {
        int e0 = i + eslot, e1 = i + 4 + eslot;
        int   c0 = __shfl(creg, e0 & 63);
        float v0 = __shfl(wreg, e0 & 63);
        int   c1 = __shfl(creg, e1 & 63);
        float v1 = __shfl(wreg, e1 & 63);
        bool a0 = e0 < m, a1 = e1 < m;
        uint4 g0, g1;
        if (a0) g0 = *(const uint4*)(h + (size_t)c0 * 128 + fg * 8);
        if (a1) g1 = *(const uint4*)(h + (size_t)c1 * 128 + fg * 8);
        if (a0) {
          float hf[8]; unpack8(g0, hf);
#pragma unroll
          for (int t = 0; t < 8; t++) acc[t] = fmaf(v0, hf[t], acc[t]);
        }
        if (a1) {
          float hf[8]; unpack8(g1, hf);
#pragma unroll
          for (int t = 0; t < 8; t++) acc[t] = fmaf(v1, hf[t], acc[t]);
        }
      }
    }
    // reduce the 4 edge-slots: lanes differing in bits 4,5 hold partials of same features
#pragma unroll
    for (int t = 0; t < 8; t++) {
      acc[t] += __shfl_xor(acc[t], 16);
      acc[t] += __shfl_xor(acc[t], 32);
    }
    if (eslot == 0) {
#pragma unroll
      for (int t = 0; t < 8; t++) acc[t] = fmaf(sd, xf[t], acc[t]);
      *(uint4*)(rel + (size_t)n * 256 + srel * 128 + fg * 8) = pack8(acc);
    }
  }
}

// HAN scores via bf16 MFMA. W1 held in registers as B-frags; A-frags direct bf16 loads.
__global__ __launch_bounds__(256) void score_mfma_kernel(
    const ushort_t* __restrict__ rel,   // [N,2,128] bf16
    const float* __restrict__ W1,       // [128,128] (k-major)
    const float* __restrict__ b1, const float* __restrict__ w2,
    float* __restrict__ s_out, int N, int nwaves) {
  int tid = threadIdx.x;
  int lane = tid & 63;
  int gw = blockIdx.x * 4 + (tid >> 6);
  int r = lane & 15;
  int kg = lane >> 4;
  bf16x8 bfr[8][4];
#pragma unroll
  for (int jt = 0; jt < 8; jt++) {
    int j = jt * 16 + r;
#pragma unroll
    for (int kt = 0; kt < 4; kt++) {
      int k0 = kt * 32 + kg * 8;
      bf16x8 v;
#pragma unroll
      for (int t = 0; t < 8; t++) v[t] = (short)f2bf(W1[(size_t)(k0 + t) * 128 + j]);
      bfr[jt][kt] = v;
    }
  }
  float b1v[8], w2v[8];
#pragma unroll
  for (int jt = 0; jt < 8; jt++) { b1v[jt] = b1[jt * 16 + r]; w2v[jt] = w2[jt * 16 + r]; }
  float s0 = 0.f, s1 = 0.f;
  int ntiles = (N + 15) >> 4;
  for (int tile = gw; tile < ntiles; tile += nwaves) {
    int n0 = tile * 16;
    int nodeA = n0 + r;
    size_t base = (size_t)((nodeA < N) ? nodeA : 0) * 256;
#pragma unroll
    for (int sub = 0; sub < 2; sub++) {
      bf16x8 afr[4];
#pragma unroll
      for (int kt = 0; kt < 4; kt++)
        afr[kt] = *(const bf16x8*)(rel + base + sub * 128 + kt * 32 + kg * 8);
      f32x4 acc[8];
#pragma unroll
      for (int jt = 0; jt < 8; jt++) acc[jt] = (f32x4){0.f, 0.f, 0.f, 0.f};
#pragma unroll
      for (int jt = 0; jt < 8; jt++)
#pragma unroll
        for (int kt = 0; kt < 4; kt++)
          acc[jt] = __builtin_amdgcn_mfma_f32_16x16x32_bf16(afr[kt], bfr[jt][kt], acc[jt], 0, 0, 0);
      float sacc = 0.f;
#pragma unroll
      for (int jt = 0; jt < 8; jt++) {
#pragma unroll
        for (int reg = 0; reg < 4; reg++) {
          int nm = n0 + kg * 4 + reg;
          if (nm < N) sacc += w2v[jt] * tanhf(acc[jt][reg] + b1v[jt]);
        }
      }
      if (sub == 0) s0 += sacc; else s1 += sacc;
    }
  }
#pragma unroll
  for (int m = 32; m >= 1; m >>= 1) { s0 += __shfl_xor(s0, m); s1 += __shfl_xor(s1, m); }
  if (lane == 0) { atomicAdd(&s_out[0], s0); atomicAdd(&s_out[1], s1); }
}

// h[n,:] = beta0*rel[n,0,:] + beta1*rel[n,1,:]; bf16 in/out, 8 feats/thread.
__global__ void combine_kernel(const ushort_t* __restrict__ rel, const float* __restrict__ s,
                               ushort_t* __restrict__ h, int N, float invN) {
  int i = blockIdx.x * blockDim.x + threadIdx.x;
  if (i >= N * 16) return;
  float m0 = s[0] * invN, m1 = s[1] * invN;
  float mx = fmaxf(m0, m1);
  float e0 = expf(m0 - mx), e1 = expf(m1 - mx);
  float inv = 1.f / (e0 + e1);
  float be0 = e0 * inv, be1 = e1 * inv;
  int n = i >> 4, q = i & 15;
  float f0[8], f1[8], o[8];
  unpack8(*(const uint4*)(rel + (size_t)n * 256 + q * 8), f0);
  unpack8(*(const uint4*)(rel + (size_t)n * 256 + 128 + q * 8), f1);
#pragma unroll
  for (int t = 0; t < 8; t++) o[t] = be0 * f0[t] + be1 * f1[t];
  *(uint4*)(h + (size_t)n * 128 + q * 8) = pack8(o);
}

// out[n,:] = h[n,:] @ W(128x64) + b   (h bf16)
__global__ void fc2_kernel(const ushort_t* __restrict__ h, const float* __restrict__ W,
                           const float* __restrict__ b, float* __restrict__ out) {
  __shared__ float hs[128];
  int n = blockIdx.x, j = threadIdx.x;  // 64 threads
  hs[j]      = bf2f(h[(size_t)n * 128 + j]);
  hs[j + 64] = bf2f(h[(size_t)n * 128 + 64 + j]);
  __syncthreads();
  float acc = b[j];
  for (int k = 0; k < 128; k++) acc = fmaf(hs[k], W[k * 64 + j], acc);
  out[(size_t)n * 64 + j] = acc;
}

extern "C" void kernel_launch(void* const* d_in, const int* in_sizes, int n_in,
                              void* d_out, int out_size, void* d_ws, size_t ws_size,
                              hipStream_t stream) {
  const float* x_paper  = (const float*)d_in[0];
  const float* x_author = (const float*)d_in[1];
  const float* fc1p_W = (const float*)d_in[2];
  const float* fc1p_b = (const float*)d_in[3];
  const float* fc1a_W = (const float*)d_in[4];
  const float* fc1a_b = (const float*)d_in[5];
  const float* fc2_W  = (const float*)d_in[6];
  const float* fc2_b  = (const float*)d_in[7];
  const float* semW1  = (const float*)d_in[8];
  const float* semb1  = (const float*)d_in[9];
  const float* semw2  = (const float*)d_in[10];
  const float* d_pp = (const float*)d_in[11];
  const float* d_pa = (const float*)d_in[12];
  const float* d_ap = (const float*)d_in[13];
  const float* d_aa = (const float*)d_in[14];
  const float* w_pp = (const float*)d_in[15];
  const float* w_pa = (const float*)d_in[16];
  const float* w_ap = (const float*)d_in[17];
  const float* w_aa = (const float*)d_in[18];
  const int* src_pp = (const int*)d_in[19];
  const int* dst_pp = (const int*)d_in[20];
  const int* src_pa = (const int*)d_in[21];
  const int* dst_pa = (const int*)d_in[22];
  const int* src_ap = (const int*)d_in[23];
  const int* dst_ap = (const int*)d_in[24];
  const int* src_aa = (const int*)d_in[25];
  const int* dst_aa = (const int*)d_in[26];

  const int Np = in_sizes[11];
  const int Na = in_sizes[13];
  const int E[4] = { in_sizes[15], in_sizes[16], in_sizes[17], in_sizes[18] };
  const int Nmax = (Np > Na) ? Np : Na;

  // workspace layout (bytes, all regions 16B-aligned)
  char* base = (char*)d_ws;
  size_t off = 0;
  ushort_t* xp = (ushort_t*)(base + off); off += (size_t)Np * 128 * 2;
  ushort_t* xa = (ushort_t*)(base + off); off += (size_t)Na * 128 * 2;
  ushort_t* hp = (ushort_t*)(base + off); off += (size_t)Np * 128 * 2;
  ushort_t* ha = (ushort_t*)(base + off); off += (size_t)Na * 128 * 2;
  ushort_t* rel = (ushort_t*)(base + off); off += (size_t)Nmax * 256 * 2;
  float* ssum = (float*)(base + off); off += 32 * 4;
  int* cnt  = (int*)(base + off); off += (size_t)(2 * Np + 2 * Na) * 4;
  int* rpB  = (int*)(base + off); off += (size_t)(2 * (Np + 1) + 2 * (Na + 1)) * 4;
  int* curB = (int*)(base + off); off += (size_t)(2 * Np + 2 * Na) * 4;
  size_t Esum = (size_t)E[0] + E[1] + E[2] + E[3];
  int* colB = (int*)(base + off); off += Esum * 4;
  float* wB = (float*)(base + off); off += Esum * 4;
  (void)ws_size; (void)n_in; (void)out_size;

  int* cnt_r[4] = { cnt, cnt + Np, cnt + (size_t)2 * Np, cnt + (size_t)2 * Np + Na };
  int* rp_r[4]  = { rpB, rpB + (Np + 1), rpB + (size_t)2 * (Np + 1),
                    rpB + (size_t)2 * (Np + 1) + (Na + 1) };
  int* cur_r[4] = { curB, curB + Np, curB + (size_t)2 * Np, curB + (size_t)2 * Np + Na };
  size_t eoff[4] = { 0, (size_t)E[0], (size_t)E[0] + E[1], (size_t)E[0] + E[1] + E[2] };
  int* col_r[4]; float* w_r[4];
  for (int r = 0; r < 4; r++) { col_r[r] = colB + eoff[r]; w_r[r] = wB + eoff[r]; }

  const int* srcs[4]    = { src_pp, src_pa, src_ap, src_aa };
  const int* dsts[4]    = { dst_pp, dst_pa, dst_ap, dst_aa };
  const float* wedge[4] = { w_pp, w_pa, w_ap, w_aa };

  int Z = 32 + 2 * Np + 2 * Na;
  zero_kernel<<<(Z + 255) / 256, 256, 0, stream>>>(ssum, Z);

  for (int r = 0; r < 4; r++)
    hist_kernel<<<(E[r] + 255) / 256, 256, 0, stream>>>(dsts[r], E[r], cnt_r[r]);
  scan4_kernel<<<4, 1024, 0, stream>>>(cnt, rpB, curB, Np, Na);
  for (int r = 0; r < 4; r++)
    scatter_kernel<<<(E[r] + 255) / 256, 256, 0, stream>>>(srcs[r], dsts[r], wedge[r],
                                                           cur_r[r], col_r[r], w_r[r], E[r]);

  fc1_kernel<256><<<(Np + 15) / 16, 256, 0, stream>>>(x_paper, fc1p_W, fc1p_b, xp, hp, Np);
  fc1_kernel<128><<<(Na + 15) / 16, 256, 0, stream>>>(x_author, fc1a_W, fc1a_b, xa, ha, Na);

  const int SCORE_BLOCKS = 128;
  const int SCORE_WAVES = SCORE_BLOCKS * 4;

  for (int i = 0; i < 5; i++) {
    // paper: pp (gather h_p), pa (gather h_a)
    float* sp = ssum + (size_t)(i * 2 + 0) * 2;
    spmm2_kernel<<<(Np + 3) / 4, 256, 0, stream>>>(xp, d_pp, d_pa, hp, ha,
        rp_r[0], col_r[0], w_r[0], rp_r[1], col_r[1], w_r[1], rel, Np);
    score_mfma_kernel<<<SCORE_BLOCKS, 256, 0, stream>>>(rel,
        semW1 + (size_t)(i * 2 + 0) * 16384, semb1 + (size_t)(i * 2 + 0) * 128,
        semw2 + (size_t)(i * 2 + 0) * 128, sp, Np, SCORE_WAVES);
    combine_kernel<<<(Np * 16 + 255) / 256, 256, 0, stream>>>(rel, sp, hp, Np, 1.f / Np);

    // author: ap (gather new h_p), aa (gather h_a)
    float* sa = ssum + (size_t)(i * 2 + 1) * 2;
    spmm2_kernel<<<(Na + 3) / 4, 256, 0, stream>>>(xa, d_ap, d_aa, hp, ha,
        rp_r[2], col_r[2], w_r[2], rp_r[3], col_r[3], w_r[3], rel, Na);
    score_mfma_kernel<<<SCORE_BLOCKS, 256, 0, stream>>>(rel,
        semW1 + (size_t)(i * 2 + 1) * 16384, semb1 + (size_t)(i * 2 + 1) * 128,
        semw2 + (size_t)(i * 2 + 1) * 128, sa, Na, SCORE_WAVES);
    combine_kernel<<<(Na * 16 + 255) / 256, 256, 0, stream>>>(rel, sa, ha, Na, 1.f / Na);
  }

  fc2_kernel<<<Np, 64, 0, stream>>>(hp, fc2_W, fc2_b, (float*)d_out);
}

// Round 4
// 3323.699 us; speedup vs baseline: 2.5913x; 1.0201x over previous
//
#include <hip/hip_runtime.h>

// HetGTCN: 5-hop heterogeneous GNN on MI355X.
//   1. CSR build for 4 relations (hist -> shfl-scan -> scatter)
//   2. fc1p/fc1a: bf16 MFMA GEMM (W in registers, grid-strided node tiles)
//   3. 5 hops x 2 types: spmm2 (bf16 gather) -> score (bf16 MFMA) -> combine
//   4. fc2 register-blocked -> d_out [Np,64] f32

typedef __attribute__((ext_vector_type(8))) short bf16x8;
typedef __attribute__((ext_vector_type(4))) float f32x4;
typedef unsigned short ushort_t;

__device__ inline unsigned short f2bf(float f) {
  union { float f; unsigned u; } x; x.f = f;
  unsigned r = x.u + 0x7fff + ((x.u >> 16) & 1);   // RNE
  return (unsigned short)(r >> 16);
}
__device__ inline float bf2f(unsigned short u) {
  union { unsigned u; float f; } x; x.u = (unsigned)u << 16; return x.f;
}
__device__ inline void unpack8(uint4 u, float* f) {
  union { unsigned u; float f; } c;
  c.u = u.x << 16;          f[0] = c.f;
  c.u = u.x & 0xffff0000u;  f[1] = c.f;
  c.u = u.y << 16;          f[2] = c.f;
  c.u = u.y & 0xffff0000u;  f[3] = c.f;
  c.u = u.z << 16;          f[4] = c.f;
  c.u = u.z & 0xffff0000u;  f[5] = c.f;
  c.u = u.w << 16;          f[6] = c.f;
  c.u = u.w & 0xffff0000u;  f[7] = c.f;
}
__device__ inline uint4 pack8(const float* f) {
  uint4 u;
  u.x = (unsigned)f2bf(f[0]) | ((unsigned)f2bf(f[1]) << 16);
  u.y = (unsigned)f2bf(f[2]) | ((unsigned)f2bf(f[3]) << 16);
  u.z = (unsigned)f2bf(f[4]) | ((unsigned)f2bf(f[5]) << 16);
  u.w = (unsigned)f2bf(f[6]) | ((unsigned)f2bf(f[7]) << 16);
  return u;
}

__global__ void zero_kernel(float* __restrict__ p, int n) {
  int i = blockIdx.x * blockDim.x + threadIdx.x;
  if (i < n) p[i] = 0.f;
}

__global__ void hist_kernel(const int* __restrict__ dst, int E, int* __restrict__ cnt) {
  int i = blockIdx.x * blockDim.x + threadIdx.x;
  if (i < E) atomicAdd(&cnt[dst[i]], 1);
}

// One block (1024 threads) per relation; shfl wave-scan, 3 barriers per 1024-chunk.
__global__ void scan4_kernel(const int* __restrict__ cnt, int* __restrict__ rp,
                             int* __restrict__ cur, int Np, int Na) {
  __shared__ int wsum[16];
  __shared__ int carry_s;
  int r = blockIdx.x;
  int N = (r < 2) ? Np : Na;
  size_t coff  = (r==0)?0 : (r==1)? (size_t)Np : (r==2)? (size_t)2*Np : (size_t)2*Np+Na;
  size_t rpoff = (r==0)?0 : (r==1)? (size_t)(Np+1) : (r==2)? (size_t)2*(Np+1) : (size_t)2*(Np+1)+(Na+1);
  const int* c = cnt + coff;
  int* rpp = rp + rpoff;
  int* cpp = cur + coff;
  int tid = threadIdx.x;
  int lane = tid & 63, wv = tid >> 6;
  if (tid == 0) carry_s = 0;
  for (int base = 0; base < N; base += 1024) {
    int i = base + tid;
    int v = (i < N) ? c[i] : 0;
    int s = v;
#pragma unroll
    for (int off = 1; off < 64; off <<= 1) {
      int t = __shfl_up(s, off);
      if (lane >= off) s += t;
    }
    if (lane == 63) wsum[wv] = s;
    __syncthreads();
    if (wv == 0 && lane < 16) {
      int p = wsum[lane];
      int q = p;
#pragma unroll
      for (int off = 1; off < 16; off <<= 1) {
        int t = __shfl_up(q, off);
        if (lane >= off) q += t;
      }
      wsum[lane] = q - p;   // exclusive wave prefix
    }
    __syncthreads();
    int carry = carry_s;
    int wexcl = wsum[wv];
    int excl = carry + wexcl + (s - v);
    if (i < N) { rpp[i] = excl; cpp[i] = excl; }
    int mytotal = wexcl + s;    // thread 1023: block total
    __syncthreads();
    if (tid == 1023) carry_s = carry + mytotal;
  }
  __syncthreads();
  if (tid == 0) rpp[N] = carry_s;
}

__global__ void scatter_kernel(const int* __restrict__ src, const int* __restrict__ dst,
                               const float* __restrict__ w, int* __restrict__ cur,
                               int* __restrict__ col, float* __restrict__ wout, int E) {
  int i = blockIdx.x * blockDim.x + threadIdx.x;
  if (i < E) {
    int p = atomicAdd(&cur[dst[i]], 1);
    col[p]  = src[i];
    wout[p] = w[i];
  }
}

// fc1 via bf16 MFMA: relu(x @ W + b) -> bf16 o1 (x table) and o2 (h table).
// KH k-halves per tile; block = 4 waves = TPB=4/KH node-tiles per iteration.
// W held in registers as B-frags (loaded once, reused over grid-strided tiles).
template<int K, int KH>
__global__ __launch_bounds__(256) void fc1_mfma_kernel(
    const float* __restrict__ x, const float* __restrict__ W,
    const float* __restrict__ b, ushort_t* __restrict__ o1, ushort_t* __restrict__ o2,
    int N) {
  constexpr int TPB = 4 / KH;
  __shared__ float cstage[4][16][128];   // 32 KB
  int tid = threadIdx.x;
  int lane = tid & 63, wid = tid >> 6;
  int tile = (KH == 2) ? (wid >> 1) : wid;
  int khalf = (KH == 2) ? (wid & 1) : 0;
  int r = lane & 15, kg = lane >> 4;
  // B-frags: W[k][j], k = khalf*128 + kt*32 + kg*8 + t, j = jt*16 + r
  bf16x8 bfr[8][4];
#pragma unroll
  for (int jt = 0; jt < 8; jt++) {
    int j = jt * 16 + r;
#pragma unroll
    for (int kt = 0; kt < 4; kt++) {
      int k0 = khalf * 128 + kt * 32 + kg * 8;
      bf16x8 v;
#pragma unroll
      for (int t = 0; t < 8; t++) v[t] = (short)f2bf(W[(size_t)(k0 + t) * 128 + j]);
      bfr[jt][kt] = v;
    }
  }
  float bb[8];
  {
    int j0 = (tid & 15) * 8;
#pragma unroll
    for (int t = 0; t < 8; t++) bb[t] = b[j0 + t];
  }
  int ntiles = (N + 15) >> 4;
  int tstride = gridDim.x * TPB;
  for (int tb = blockIdx.x * TPB; tb < ntiles; tb += tstride) {
    int mytile = tb + tile;
    int nodeA = mytile * 16 + r;
    if (nodeA >= N) nodeA = 0;                  // clamp; masked at store
    const float* xrow = x + (size_t)nodeA * K + khalf * 128;
    bf16x8 afr[4];
#pragma unroll
    for (int kt = 0; kt < 4; kt++) {
      const float4* p = (const float4*)(xrow + kt * 32 + kg * 8);
      float4 lo = p[0], hi = p[1];
      bf16x8 v;
      v[0] = (short)f2bf(lo.x); v[1] = (short)f2bf(lo.y);
      v[2] = (short)f2bf(lo.z); v[3] = (short)f2bf(lo.w);
      v[4] = (short)f2bf(hi.x); v[5] = (short)f2bf(hi.y);
      v[6] = (short)f2bf(hi.z); v[7] = (short)f2bf(hi.w);
      afr[kt] = v;
    }
    f32x4 acc[8];
#pragma unroll
    for (int jt = 0; jt < 8; jt++) acc[jt] = (f32x4){0.f, 0.f, 0.f, 0.f};
#pragma unroll
    for (int jt = 0; jt < 8; jt++)
#pragma unroll
      for (int kt = 0; kt < 4; kt++)
        acc[jt] = __builtin_amdgcn_mfma_f32_16x16x32_bf16(afr[kt], bfr[jt][kt], acc[jt], 0, 0, 0);
    // C layout: col j = jt*16 + (lane&15), row node = kg*4 + reg
#pragma unroll
    for (int jt = 0; jt < 8; jt++)
#pragma unroll
      for (int reg = 0; reg < 4; reg++)
        cstage[wid][kg * 4 + reg][jt * 16 + r] = acc[jt][reg];
    __syncthreads();
    // finish: reduce k-halves, +bias, relu, bf16 pack, coalesced store
    int node = tid >> 4, j0 = (tid & 15) * 8;
#pragma unroll
    for (int it = 0; it < TPB; it++) {
      int n = (tb + it) * 16 + node;
      float f[8];
#pragma unroll
      for (int t = 0; t < 8; t++) {
        float v = cstage[it * KH][node][j0 + t];
        if (KH == 2) v += cstage[it * 2 + 1][node][j0 + t];
        f[t] = fmaxf(v + bb[t], 0.f);
      }
      if (n < N) {
        uint4 pk = pack8(f);
        *(uint4*)(o1 + (size_t)n * 128 + j0) = pk;
        *(uint4*)(o2 + (size_t)n * 128 + j0) = pk;
      }
    }
    __syncthreads();
  }
}

// Wave-per-node SPMM over 2 relations, bf16 rows (256B): 16 lanes x 16B per row,
// 4 edges per wave-issue (eslot = lane>>4), 2-quad unrolled for MLP.
__global__ __launch_bounds__(256) void spmm2_kernel(
    const ushort_t* __restrict__ xself,
    const float* __restrict__ d0, const float* __restrict__ d1,
    const ushort_t* __restrict__ h0, const ushort_t* __restrict__ h1,
    const int* __restrict__ rp0, const int* __restrict__ col0, const float* __restrict__ w0,
    const int* __restrict__ rp1, const int* __restrict__ col1, const float* __restrict__ w1,
    ushort_t* __restrict__ rel, int N) {
  int tid = threadIdx.x;
  int lane = tid & 63, wid = tid >> 6;
  int fg = lane & 15;
  int eslot = lane >> 4;
  int n = blockIdx.x * 4 + wid;
  if (n >= N) return;
  float xf[8];
  unpack8(*(const uint4*)(xself + (size_t)n * 128 + fg * 8), xf);
#pragma unroll
  for (int srel = 0; srel < 2; srel++) {
    const float sd = srel ? d1[n] : d0[n];
    const int* rp = srel ? rp1 : rp0;
    const int* col = srel ? col1 : col0;
    const float* wv_arr = srel ? w1 : w0;
    const ushort_t* h = srel ? h1 : h0;
    float acc[8];
#pragma unroll
    for (int t = 0; t < 8; t++) acc[t] = 0.f;
    int beg = rp[n], end = rp[n + 1];
    for (int cb = beg; cb < end; cb += 64) {
      int m = end - cb; if (m > 64) m = 64;
      int creg = 0; float wreg = 0.f;
      if (lane < m) { creg = col[cb + lane]; wreg = wv_arr[cb + lane]; }
      for (int i = 0; i < m; i += 8) {
        int e0 = i + eslot, e1 = i + 4 + eslot;
        int   c0 = __shfl(creg, e0 & 63);
        float v0 = __shfl(wreg, e0 & 63);
        int   c1 = __shfl(creg, e1 & 63);
        float v1 = __shfl(wreg, e1 & 63);
        bool a0 = e0 < m, a1 = e1 < m;
        uint4 g0, g1;
        if (a0) g0 = *(const uint4*)(h + (size_t)c0 * 128 + fg * 8);
        if (a1) g1 = *(const uint4*)(h + (size_t)c1 * 128 + fg * 8);
        if (a0) {
          float hf[8]; unpack8(g0, hf);
#pragma unroll
          for (int t = 0; t < 8; t++) acc[t] = fmaf(v0, hf[t], acc[t]);
        }
        if (a1) {
          float hf[8]; unpack8(g1, hf);
#pragma unroll
          for (int t = 0; t < 8; t++) acc[t] = fmaf(v1, hf[t], acc[t]);
        }
      }
    }
#pragma unroll
    for (int t = 0; t < 8; t++) {
      acc[t] += __shfl_xor(acc[t], 16);
      acc[t] += __shfl_xor(acc[t], 32);
    }
    if (eslot == 0) {
#pragma unroll
      for (int t = 0; t < 8; t++) acc[t] = fmaf(sd, xf[t], acc[t]);
      *(uint4*)(rel + (size_t)n * 256 + srel * 128 + fg * 8) = pack8(acc);
    }
  }
}

// HAN scores via bf16 MFMA. W1 held in registers as B-frags; A-frags direct bf16 loads.
__global__ __launch_bounds__(256) void score_mfma_kernel(
    const ushort_t* __restrict__ rel,   // [N,2,128] bf16
    const float* __restrict__ W1,       // [128,128] (k-major)
    const float* __restrict__ b1, const float* __restrict__ w2,
    float* __restrict__ s_out, int N, int nwaves) {
  int tid = threadIdx.x;
  int lane = tid & 63;
  int gw = blockIdx.x * 4 + (tid >> 6);
  int r = lane & 15;
  int kg = lane >> 4;
  bf16x8 bfr[8][4];
#pragma unroll
  for (int jt = 0; jt < 8; jt++) {
    int j = jt * 16 + r;
#pragma unroll
    for (int kt = 0; kt < 4; kt++) {
      int k0 = kt * 32 + kg * 8;
      bf16x8 v;
#pragma unroll
      for (int t = 0; t < 8; t++) v[t] = (short)f2bf(W1[(size_t)(k0 + t) * 128 + j]);
      bfr[jt][kt] = v;
    }
  }
  float b1v[8], w2v[8];
#pragma unroll
  for (int jt = 0; jt < 8; jt++) { b1v[jt] = b1[jt * 16 + r]; w2v[jt] = w2[jt * 16 + r]; }
  float s0 = 0.f, s1 = 0.f;
  int ntiles = (N + 15) >> 4;
  for (int tile = gw; tile < ntiles; tile += nwaves) {
    int n0 = tile * 16;
    int nodeA = n0 + r;
    size_t base = (size_t)((nodeA < N) ? nodeA : 0) * 256;
#pragma unroll
    for (int sub = 0; sub < 2; sub++) {
      bf16x8 afr[4];
#pragma unroll
      for (int kt = 0; kt < 4; kt++)
        afr[kt] = *(const bf16x8*)(rel + base + sub * 128 + kt * 32 + kg * 8);
      f32x4 acc[8];
#pragma unroll
      for (int jt = 0; jt < 8; jt++) acc[jt] = (f32x4){0.f, 0.f, 0.f, 0.f};
#pragma unroll
      for (int jt = 0; jt < 8; jt++)
#pragma unroll
        for (int kt = 0; kt < 4; kt++)
          acc[jt] = __builtin_amdgcn_mfma_f32_16x16x32_bf16(afr[kt], bfr[jt][kt], acc[jt], 0, 0, 0);
      float sacc = 0.f;
#pragma unroll
      for (int jt = 0; jt < 8; jt++) {
#pragma unroll
        for (int reg = 0; reg < 4; reg++) {
          int nm = n0 + kg * 4 + reg;
          if (nm < N) sacc += w2v[jt] * tanhf(acc[jt][reg] + b1v[jt]);
        }
      }
      if (sub == 0) s0 += sacc; else s1 += sacc;
    }
  }
#pragma unroll
  for (int m = 32; m >= 1; m >>= 1) { s0 += __shfl_xor(s0, m); s1 += __shfl_xor(s1, m); }
  if (lane == 0) { atomicAdd(&s_out[0], s0); atomicAdd(&s_out[1], s1); }
}

// h[n,:] = beta0*rel[n,0,:] + beta1*rel[n,1,:]; bf16 in/out, 8 feats/thread.
__global__ void combine_kernel(const ushort_t* __restrict__ rel, const float* __restrict__ s,
                               ushort_t* __restrict__ h, int N, float invN) {
  int i = blockIdx.x * blockDim.x + threadIdx.x;
  if (i >= N * 16) return;
  float m0 = s[0] * invN, m1 = s[1] * invN;
  float mx = fmaxf(m0, m1);
  float e0 = expf(m0 - mx), e1 = expf(m1 - mx);
  float inv = 1.f / (e0 + e1);
  float be0 = e0 * inv, be1 = e1 * inv;
  int n = i >> 4, q = i & 15;
  float f0[8], f1[8], o[8];
  unpack8(*(const uint4*)(rel + (size_t)n * 256 + q * 8), f0);
  unpack8(*(const uint4*)(rel + (size_t)n * 256 + 128 + q * 8), f1);
#pragma unroll
  for (int t = 0; t < 8; t++) o[t] = be0 * f0[t] + be1 * f1[t];
  *(uint4*)(h + (size_t)n * 128 + q * 8) = pack8(o);
}

// out = h @ W(128x64) + b; 16 nodes/block, 256 threads (64 f x 4 node-groups).
__global__ __launch_bounds__(256) void fc2_kernel(const ushort_t* __restrict__ h,
    const float* __restrict__ W, const float* __restrict__ b,
    float* __restrict__ out, int N) {
  __shared__ float hs[16][132];
  int tid = threadIdx.x;
  int n0 = blockIdx.x * 16;
  {
    int node = tid >> 4, k0 = (tid & 15) * 8;
    int n = n0 + node;
    float f[8];
    if (n < N) unpack8(*(const uint4*)(h + (size_t)n * 128 + k0), f);
    else {
#pragma unroll
      for (int t = 0; t < 8; t++) f[t] = 0.f;
    }
#pragma unroll
    for (int t = 0; t < 8; t++) hs[node][k0 + t] = f[t];
  }
  __syncthreads();
  int f = tid & 63, g = tid >> 6;
  float bv = b[f];
  float acc[4];
#pragma unroll
  for (int rr = 0; rr < 4; rr++) acc[rr] = bv;
  for (int k = 0; k < 128; k += 4) {
    float w0 = W[(size_t)k * 64 + f];
    float w1 = W[(size_t)(k + 1) * 64 + f];
    float w2 = W[(size_t)(k + 2) * 64 + f];
    float w3 = W[(size_t)(k + 3) * 64 + f];
#pragma unroll
    for (int rr = 0; rr < 4; rr++) {
      float4 hv = *(const float4*)&hs[g * 4 + rr][k];
      acc[rr] = fmaf(hv.x, w0, acc[rr]);
      acc[rr] = fmaf(hv.y, w1, acc[rr]);
      acc[rr] = fmaf(hv.z, w2, acc[rr]);
      acc[rr] = fmaf(hv.w, w3, acc[rr]);
    }
  }
#pragma unroll
  for (int rr = 0; rr < 4; rr++) {
    int n = n0 + g * 4 + rr;
    if (n < N) out[(size_t)n * 64 + f] = acc[rr];
  }
}

extern "C" void kernel_launch(void* const* d_in, const int* in_sizes, int n_in,
                              void* d_out, int out_size, void* d_ws, size_t ws_size,
                              hipStream_t stream) {
  const float* x_paper  = (const float*)d_in[0];
  const float* x_author = (const float*)d_in[1];
  const float* fc1p_W = (const float*)d_in[2];
  const float* fc1p_b = (const float*)d_in[3];
  const float* fc1a_W = (const float*)d_in[4];
  const float* fc1a_b = (const float*)d_in[5];
  const float* fc2_W  = (const float*)d_in[6];
  const float* fc2_b  = (const float*)d_in[7];
  const float* semW1  = (const float*)d_in[8];
  const float* semb1  = (const float*)d_in[9];
  const float* semw2  = (const float*)d_in[10];
  const float* d_pp = (const float*)d_in[11];
  const float* d_pa = (const float*)d_in[12];
  const float* d_ap = (const float*)d_in[13];
  const float* d_aa = (const float*)d_in[14];
  const float* w_pp = (const float*)d_in[15];
  const float* w_pa = (const float*)d_in[16];
  const float* w_ap = (const float*)d_in[17];
  const float* w_aa = (const float*)d_in[18];
  const int* src_pp = (const int*)d_in[19];
  const int* dst_pp = (const int*)d_in[20];
  const int* src_pa = (const int*)d_in[21];
  const int* dst_pa = (const int*)d_in[22];
  const int* src_ap = (const int*)d_in[23];
  const int* dst_ap = (const int*)d_in[24];
  const int* src_aa = (const int*)d_in[25];
  const int* dst_aa = (const int*)d_in[26];

  const int Np = in_sizes[11];
  const int Na = in_sizes[13];
  const int E[4] = { in_sizes[15], in_sizes[16], in_sizes[17], in_sizes[18] };
  const int Nmax = (Np > Na) ? Np : Na;

  char* base = (char*)d_ws;
  size_t off = 0;
  ushort_t* xp = (ushort_t*)(base + off); off += (size_t)Np * 128 * 2;
  ushort_t* xa = (ushort_t*)(base + off); off += (size_t)Na * 128 * 2;
  ushort_t* hp = (ushort_t*)(base + off); off += (size_t)Np * 128 * 2;
  ushort_t* ha = (ushort_t*)(base + off); off += (size_t)Na * 128 * 2;
  ushort_t* rel = (ushort_t*)(base + off); off += (size_t)Nmax * 256 * 2;
  float* ssum = (float*)(base + off); off += 32 * 4;
  int* cnt  = (int*)(base + off); off += (size_t)(2 * Np + 2 * Na) * 4;
  int* rpB  = (int*)(base + off); off += (size_t)(2 * (Np + 1) + 2 * (Na + 1)) * 4;
  int* curB = (int*)(base + off); off += (size_t)(2 * Np + 2 * Na) * 4;
  size_t Esum = (size_t)E[0] + E[1] + E[2] + E[3];
  int* colB = (int*)(base + off); off += Esum * 4;
  float* wB = (float*)(base + off); off += Esum * 4;
  (void)ws_size; (void)n_in; (void)out_size;

  int* cnt_r[4] = { cnt, cnt + Np, cnt + (size_t)2 * Np, cnt + (size_t)2 * Np + Na };
  int* rp_r[4]  = { rpB, rpB + (Np + 1), rpB + (size_t)2 * (Np + 1),
                    rpB + (size_t)2 * (Np + 1) + (Na + 1) };
  int* cur_r[4] = { curB, curB + Np, curB + (size_t)2 * Np, curB + (size_t)2 * Np + Na };
  size_t eoff[4] = { 0, (size_t)E[0], (size_t)E[0] + E[1], (size_t)E[0] + E[1] + E[2] };
  int* col_r[4]; float* w_r[4];
  for (int r = 0; r < 4; r++) { col_r[r] = colB + eoff[r]; w_r[r] = wB + eoff[r]; }

  const int* srcs[4]    = { src_pp, src_pa, src_ap, src_aa };
  const int* dsts[4]    = { dst_pp, dst_pa, dst_ap, dst_aa };
  const float* wedge[4] = { w_pp, w_pa, w_ap, w_aa };

  int Z = 32 + 2 * Np + 2 * Na;
  zero_kernel<<<(Z + 255) / 256, 256, 0, stream>>>(ssum, Z);

  for (int r = 0; r < 4; r++)
    hist_kernel<<<(E[r] + 255) / 256, 256, 0, stream>>>(dsts[r], E[r], cnt_r[r]);
  scan4_kernel<<<4, 1024, 0, stream>>>(cnt, rpB, curB, Np, Na);
  for (int r = 0; r < 4; r++)
    scatter_kernel<<<(E[r] + 255) / 256, 256, 0, stream>>>(srcs[r], dsts[r], wedge[r],
                                                           cur_r[r], col_r[r], w_r[r], E[r]);

  fc1_mfma_kernel<256, 2><<<256, 256, 0, stream>>>(x_paper, fc1p_W, fc1p_b, xp, hp, Np);
  fc1_mfma_kernel<128, 1><<<256, 256, 0, stream>>>(x_author, fc1a_W, fc1a_b, xa, ha, Na);

  const int SCORE_BLOCKS = 128;
  const int SCORE_WAVES = SCORE_BLOCKS * 4;

  for (int i = 0; i < 5; i++) {
    // paper: pp (gather h_p), pa (gather h_a)
    float* sp = ssum + (size_t)(i * 2 + 0) * 2;
    spmm2_kernel<<<(Np + 3) / 4, 256, 0, stream>>>(xp, d_pp, d_pa, hp, ha,
        rp_r[0], col_r[0], w_r[0], rp_r[1], col_r[1], w_r[1], rel, Np);
    score_mfma_kernel<<<SCORE_BLOCKS, 256, 0, stream>>>(rel,
        semW1 + (size_t)(i * 2 + 0) * 16384, semb1 + (size_t)(i * 2 + 0) * 128,
        semw2 + (size_t)(i * 2 + 0) * 128, sp, Np, SCORE_WAVES);
    combine_kernel<<<(Np * 16 + 255) / 256, 256, 0, stream>>>(rel, sp, hp, Np, 1.f / Np);

    // author: ap (gather new h_p), aa (gather h_a)
    float* sa = ssum + (size_t)(i * 2 + 1) * 2;
    spmm2_kernel<<<(Na + 3) / 4, 256, 0, stream>>>(xa, d_ap, d_aa, hp, ha,
        rp_r[2], col_r[2], w_r[2], rp_r[3], col_r[3], w_r[3], rel, Na);
    score_mfma_kernel<<<SCORE_BLOCKS, 256, 0, stream>>>(rel,
        semW1 + (size_t)(i * 2 + 1) * 16384, semb1 + (size_t)(i * 2 + 1) * 128,
        semw2 + (size_t)(i * 2 + 1) * 128, sa, Na, SCORE_WAVES);
    combine_kernel<<<(Na * 16 + 255) / 256, 256, 0, stream>>>(rel, sa, ha, Na, 1.f / Na);
  }

  fc2_kernel<<<(Np + 15) / 16, 256, 0, stream>>>(hp, fc2_W, fc2_b, (float*)d_out, Np);
}

// Round 5
// 3024.532 us; speedup vs baseline: 2.8477x; 1.0989x over previous
//
#include <hip/hip_runtime.h>

// HetGTCN: 5-hop heterogeneous GNN on MI355X.
//   1. CSR build for 4 relations (hist -> shfl-scan -> scatter)
//   2. fc1p/fc1a: bf16 MFMA GEMM (W in registers, grid-strided node tiles)
//   3. 5 hops x 2 types: spmm2 (bf16 gather) -> score (bf16 MFMA) -> combine
//   4. fc2: bf16 MFMA (W2 in registers) -> d_out [Np,64] f32
// NOTE (round-4 lesson): register-blocked VALU fc2 spilled (VGPR=256, 743MB scratch
// writes). MFMA + weights-in-registers is the pattern that works for all dense layers.

typedef __attribute__((ext_vector_type(8))) short bf16x8;
typedef __attribute__((ext_vector_type(4))) float f32x4;
typedef unsigned short ushort_t;

__device__ inline unsigned short f2bf(float f) {
  union { float f; unsigned u; } x; x.f = f;
  unsigned r = x.u + 0x7fff + ((x.u >> 16) & 1);   // RNE
  return (unsigned short)(r >> 16);
}
__device__ inline float bf2f(unsigned short u) {
  union { unsigned u; float f; } x; x.u = (unsigned)u << 16; return x.f;
}
__device__ inline void unpack8(uint4 u, float* f) {
  union { unsigned u; float f; } c;
  c.u = u.x << 16;          f[0] = c.f;
  c.u = u.x & 0xffff0000u;  f[1] = c.f;
  c.u = u.y << 16;          f[2] = c.f;
  c.u = u.y & 0xffff0000u;  f[3] = c.f;
  c.u = u.z << 16;          f[4] = c.f;
  c.u = u.z & 0xffff0000u;  f[5] = c.f;
  c.u = u.w << 16;          f[6] = c.f;
  c.u = u.w & 0xffff0000u;  f[7] = c.f;
}
__device__ inline uint4 pack8(const float* f) {
  uint4 u;
  u.x = (unsigned)f2bf(f[0]) | ((unsigned)f2bf(f[1]) << 16);
  u.y = (unsigned)f2bf(f[2]) | ((unsigned)f2bf(f[3]) << 16);
  u.z = (unsigned)f2bf(f[4]) | ((unsigned)f2bf(f[5]) << 16);
  u.w = (unsigned)f2bf(f[6]) | ((unsigned)f2bf(f[7]) << 16);
  return u;
}

__global__ void zero_kernel(float* __restrict__ p, int n) {
  int i = blockIdx.x * blockDim.x + threadIdx.x;
  if (i < n) p[i] = 0.f;
}

__global__ void hist_kernel(const int* __restrict__ dst, int E, int* __restrict__ cnt) {
  int i = blockIdx.x * blockDim.x + threadIdx.x;
  if (i < E) atomicAdd(&cnt[dst[i]], 1);
}

// One block (1024 threads) per relation; shfl wave-scan, 3 barriers per 1024-chunk.
__global__ void scan4_kernel(const int* __restrict__ cnt, int* __restrict__ rp,
                             int* __restrict__ cur, int Np, int Na) {
  __shared__ int wsum[16];
  __shared__ int carry_s;
  int r = blockIdx.x;
  int N = (r < 2) ? Np : Na;
  size_t coff  = (r==0)?0 : (r==1)? (size_t)Np : (r==2)? (size_t)2*Np : (size_t)2*Np+Na;
  size_t rpoff = (r==0)?0 : (r==1)? (size_t)(Np+1) : (r==2)? (size_t)2*(Np+1) : (size_t)2*(Np+1)+(Na+1);
  const int* c = cnt + coff;
  int* rpp = rp + rpoff;
  int* cpp = cur + coff;
  int tid = threadIdx.x;
  int lane = tid & 63, wv = tid >> 6;
  if (tid == 0) carry_s = 0;
  for (int base = 0; base < N; base += 1024) {
    int i = base + tid;
    int v = (i < N) ? c[i] : 0;
    int s = v;
#pragma unroll
    for (int off = 1; off < 64; off <<= 1) {
      int t = __shfl_up(s, off);
      if (lane >= off) s += t;
    }
    if (lane == 63) wsum[wv] = s;
    __syncthreads();
    if (wv == 0 && lane < 16) {
      int p = wsum[lane];
      int q = p;
#pragma unroll
      for (int off = 1; off < 16; off <<= 1) {
        int t = __shfl_up(q, off);
        if (lane >= off) q += t;
      }
      wsum[lane] = q - p;   // exclusive wave prefix
    }
    __syncthreads();
    int carry = carry_s;
    int wexcl = wsum[wv];
    int excl = carry + wexcl + (s - v);
    if (i < N) { rpp[i] = excl; cpp[i] = excl; }
    int mytotal = wexcl + s;
    __syncthreads();
    if (tid == 1023) carry_s = carry + mytotal;
  }
  __syncthreads();
  if (tid == 0) rpp[N] = carry_s;
}

__global__ void scatter_kernel(const int* __restrict__ src, const int* __restrict__ dst,
                               const float* __restrict__ w, int* __restrict__ cur,
                               int* __restrict__ col, float* __restrict__ wout, int E) {
  int i = blockIdx.x * blockDim.x + threadIdx.x;
  if (i < E) {
    int p = atomicAdd(&cur[dst[i]], 1);
    col[p]  = src[i];
    wout[p] = w[i];
  }
}

// fc1 via bf16 MFMA: relu(x @ W + b) -> bf16 o1 (x table) and o2 (h table).
template<int K, int KH>
__global__ __launch_bounds__(256) void fc1_mfma_kernel(
    const float* __restrict__ x, const float* __restrict__ W,
    const float* __restrict__ b, ushort_t* __restrict__ o1, ushort_t* __restrict__ o2,
    int N) {
  constexpr int TPB = 4 / KH;
  __shared__ float cstage[4][16][128];   // 32 KB
  int tid = threadIdx.x;
  int lane = tid & 63, wid = tid >> 6;
  int tile = (KH == 2) ? (wid >> 1) : wid;
  int khalf = (KH == 2) ? (wid & 1) : 0;
  int r = lane & 15, kg = lane >> 4;
  bf16x8 bfr[8][4];
#pragma unroll
  for (int jt = 0; jt < 8; jt++) {
    int j = jt * 16 + r;
#pragma unroll
    for (int kt = 0; kt < 4; kt++) {
      int k0 = khalf * 128 + kt * 32 + kg * 8;
      bf16x8 v;
#pragma unroll
      for (int t = 0; t < 8; t++) v[t] = (short)f2bf(W[(size_t)(k0 + t) * 128 + j]);
      bfr[jt][kt] = v;
    }
  }
  float bb[8];
  {
    int j0 = (tid & 15) * 8;
#pragma unroll
    for (int t = 0; t < 8; t++) bb[t] = b[j0 + t];
  }
  int ntiles = (N + 15) >> 4;
  int tstride = gridDim.x * TPB;
  for (int tb = blockIdx.x * TPB; tb < ntiles; tb += tstride) {
    int mytile = tb + tile;
    int nodeA = mytile * 16 + r;
    if (nodeA >= N) nodeA = 0;
    const float* xrow = x + (size_t)nodeA * K + khalf * 128;
    bf16x8 afr[4];
#pragma unroll
    for (int kt = 0; kt < 4; kt++) {
      const float4* p = (const float4*)(xrow + kt * 32 + kg * 8);
      float4 lo = p[0], hi = p[1];
      bf16x8 v;
      v[0] = (short)f2bf(lo.x); v[1] = (short)f2bf(lo.y);
      v[2] = (short)f2bf(lo.z); v[3] = (short)f2bf(lo.w);
      v[4] = (short)f2bf(hi.x); v[5] = (short)f2bf(hi.y);
      v[6] = (short)f2bf(hi.z); v[7] = (short)f2bf(hi.w);
      afr[kt] = v;
    }
    f32x4 acc[8];
#pragma unroll
    for (int jt = 0; jt < 8; jt++) acc[jt] = (f32x4){0.f, 0.f, 0.f, 0.f};
#pragma unroll
    for (int jt = 0; jt < 8; jt++)
#pragma unroll
      for (int kt = 0; kt < 4; kt++)
        acc[jt] = __builtin_amdgcn_mfma_f32_16x16x32_bf16(afr[kt], bfr[jt][kt], acc[jt], 0, 0, 0);
#pragma unroll
    for (int jt = 0; jt < 8; jt++)
#pragma unroll
      for (int reg = 0; reg < 4; reg++)
        cstage[wid][kg * 4 + reg][jt * 16 + r] = acc[jt][reg];
    __syncthreads();
    int node = tid >> 4, j0 = (tid & 15) * 8;
#pragma unroll
    for (int it = 0; it < TPB; it++) {
      int n = (tb + it) * 16 + node;
      float f[8];
#pragma unroll
      for (int t = 0; t < 8; t++) {
        float v = cstage[it * KH][node][j0 + t];
        if (KH == 2) v += cstage[it * 2 + 1][node][j0 + t];
        f[t] = fmaxf(v + bb[t], 0.f);
      }
      if (n < N) {
        uint4 pk = pack8(f);
        *(uint4*)(o1 + (size_t)n * 128 + j0) = pk;
        *(uint4*)(o2 + (size_t)n * 128 + j0) = pk;
      }
    }
    __syncthreads();
  }
}

// Wave-per-node SPMM over 2 relations, bf16 rows (256B): 16 lanes x 16B per row,
// 4 edges per wave-issue (eslot = lane>>4), 2-quad unrolled for MLP.
__global__ __launch_bounds__(256) void spmm2_kernel(
    const ushort_t* __restrict__ xself,
    const float* __restrict__ d0, const float* __restrict__ d1,
    const ushort_t* __restrict__ h0, const ushort_t* __restrict__ h1,
    const int* __restrict__ rp0, const int* __restrict__ col0, const float* __restrict__ w0,
    const int* __restrict__ rp1, const int* __restrict__ col1, const float* __restrict__ w1,
    ushort_t* __restrict__ rel, int N) {
  int tid = threadIdx.x;
  int lane = tid & 63, wid = tid >> 6;
  int fg = lane & 15;
  int eslot = lane >> 4;
  int n = blockIdx.x * 4 + wid;
  if (n >= N) return;
  float xf[8];
  unpack8(*(const uint4*)(xself + (size_t)n * 128 + fg * 8), xf);
#pragma unroll
  for (int srel = 0; srel < 2; srel++) {
    const float sd = srel ? d1[n] : d0[n];
    const int* rp = srel ? rp1 : rp0;
    const int* col = srel ? col1 : col0;
    const float* wv_arr = srel ? w1 : w0;
    const ushort_t* h = srel ? h1 : h0;
    float acc[8];
#pragma unroll
    for (int t = 0; t < 8; t++) acc[t] = 0.f;
    int beg = rp[n], end = rp[n + 1];
    for (int cb = beg; cb < end; cb += 64) {
      int m = end - cb; if (m > 64) m = 64;
      int creg = 0; float wreg = 0.f;
      if (lane < m) { creg = col[cb + lane]; wreg = wv_arr[cb + lane]; }
      for (int i = 0; i < m; i += 8) {
        int e0 = i + eslot, e1 = i + 4 + eslot;
        int   c0 = __shfl(creg, e0 & 63);
        float v0 = __shfl(wreg, e0 & 63);
        int   c1 = __shfl(creg, e1 & 63);
        float v1 = __shfl(wreg, e1 & 63);
        bool a0 = e0 < m, a1 = e1 < m;
        uint4 g0, g1;
        if (a0) g0 = *(const uint4*)(h + (size_t)c0 * 128 + fg * 8);
        if (a1) g1 = *(const uint4*)(h + (size_t)c1 * 128 + fg * 8);
        if (a0) {
          float hf[8]; unpack8(g0, hf);
#pragma unroll
          for (int t = 0; t < 8; t++) acc[t] = fmaf(v0, hf[t], acc[t]);
        }
        if (a1) {
          float hf[8]; unpack8(g1, hf);
#pragma unroll
          for (int t = 0; t < 8; t++) acc[t] = fmaf(v1, hf[t], acc[t]);
        }
      }
    }
#pragma unroll
    for (int t = 0; t < 8; t++) {
      acc[t] += __shfl_xor(acc[t], 16);
      acc[t] += __shfl_xor(acc[t], 32);
    }
    if (eslot == 0) {
#pragma unroll
      for (int t = 0; t < 8; t++) acc[t] = fmaf(sd, xf[t], acc[t]);
      *(uint4*)(rel + (size_t)n * 256 + srel * 128 + fg * 8) = pack8(acc);
    }
  }
}

// HAN scores via bf16 MFMA. W1 held in registers as B-frags; A-frags direct bf16 loads.
__global__ __launch_bounds__(256) void score_mfma_kernel(
    const ushort_t* __restrict__ rel,   // [N,2,128] bf16
    const float* __restrict__ W1,       // [128,128] (k-major)
    const float* __restrict__ b1, const float* __restrict__ w2,
    float* __restrict__ s_out, int N, int nwaves) {
  int tid = threadIdx.x;
  int lane = tid & 63;
  int gw = blockIdx.x * 4 + (tid >> 6);
  int r = lane & 15;
  int kg = lane >> 4;
  bf16x8 bfr[8][4];
#pragma unroll
  for (int jt = 0; jt < 8; jt++) {
    int j = jt * 16 + r;
#pragma unroll
    for (int kt = 0; kt < 4; kt++) {
      int k0 = kt * 32 + kg * 8;
      bf16x8 v;
#pragma unroll
      for (int t = 0; t < 8; t++) v[t] = (short)f2bf(W1[(size_t)(k0 + t) * 128 + j]);
      bfr[jt][kt] = v;
    }
  }
  float b1v[8], w2v[8];
#pragma unroll
  for (int jt = 0; jt < 8; jt++) { b1v[jt] = b1[jt * 16 + r]; w2v[jt] = w2[jt * 16 + r]; }
  float s0 = 0.f, s1 = 0.f;
  int ntiles = (N + 15) >> 4;
  for (int tile = gw; tile < ntiles; tile += nwaves) {
    int n0 = tile * 16;
    int nodeA = n0 + r;
    size_t base = (size_t)((nodeA < N) ? nodeA : 0) * 256;
#pragma unroll
    for (int sub = 0; sub < 2; sub++) {
      bf16x8 afr[4];
#pragma unroll
      for (int kt = 0; kt < 4; kt++)
        afr[kt] = *(const bf16x8*)(rel + base + sub * 128 + kt * 32 + kg * 8);
      f32x4 acc[8];
#pragma unroll
      for (int jt = 0; jt < 8; jt++) acc[jt] = (f32x4){0.f, 0.f, 0.f, 0.f};
#pragma unroll
      for (int jt = 0; jt < 8; jt++)
#pragma unroll
        for (int kt = 0; kt < 4; kt++)
          acc[jt] = __builtin_amdgcn_mfma_f32_16x16x32_bf16(afr[kt], bfr[jt][kt], acc[jt], 0, 0, 0);
      float sacc = 0.f;
#pragma unroll
      for (int jt = 0; jt < 8; jt++) {
#pragma unroll
        for (int reg = 0; reg < 4; reg++) {
          int nm = n0 + kg * 4 + reg;
          if (nm < N) sacc += w2v[jt] * tanhf(acc[jt][reg] + b1v[jt]);
        }
      }
      if (sub == 0) s0 += sacc; else s1 += sacc;
    }
  }
#pragma unroll
  for (int m = 32; m >= 1; m >>= 1) { s0 += __shfl_xor(s0, m); s1 += __shfl_xor(s1, m); }
  if (lane == 0) { atomicAdd(&s_out[0], s0); atomicAdd(&s_out[1], s1); }
}

// h[n,:] = beta0*rel[n,0,:] + beta1*rel[n,1,:]; bf16 in/out, 8 feats/thread.
__global__ void combine_kernel(const ushort_t* __restrict__ rel, const float* __restrict__ s,
                               ushort_t* __restrict__ h, int N, float invN) {
  int i = blockIdx.x * blockDim.x + threadIdx.x;
  if (i >= N * 16) return;
  float m0 = s[0] * invN, m1 = s[1] * invN;
  float mx = fmaxf(m0, m1);
  float e0 = expf(m0 - mx), e1 = expf(m1 - mx);
  float inv = 1.f / (e0 + e1);
  float be0 = e0 * inv, be1 = e1 * inv;
  int n = i >> 4, q = i & 15;
  float f0[8], f1[8], o[8];
  unpack8(*(const uint4*)(rel + (size_t)n * 256 + q * 8), f0);
  unpack8(*(const uint4*)(rel + (size_t)n * 256 + 128 + q * 8), f1);
#pragma unroll
  for (int t = 0; t < 8; t++) o[t] = be0 * f0[t] + be1 * f1[t];
  *(uint4*)(h + (size_t)n * 128 + q * 8) = pack8(o);
}

// fc2 via bf16 MFMA: out = h @ W2(128x64) + b2. Wave = 16-node tile, grid-strided;
// W2 as B-frags in registers (4 j-tiles x 4 k-tiles), A-frags direct bf16 h loads.
__global__ __launch_bounds__(256) void fc2_mfma_kernel(
    const ushort_t* __restrict__ h,     // [N,128] bf16
    const float* __restrict__ W,        // [128,64]
    const float* __restrict__ b,        // [64]
    float* __restrict__ out, int N, int nwaves) {
  int tid = threadIdx.x;
  int lane = tid & 63;
  int gw = blockIdx.x * 4 + (tid >> 6);
  int r = lane & 15, kg = lane >> 4;
  bf16x8 bfr[4][4];
#pragma unroll
  for (int jt = 0; jt < 4; jt++) {
    int j = jt * 16 + r;
#pragma unroll
    for (int kt = 0; kt < 4; kt++) {
      int k0 = kt * 32 + kg * 8;
      bf16x8 v;
#pragma unroll
      for (int t = 0; t < 8; t++) v[t] = (short)f2bf(W[(size_t)(k0 + t) * 64 + j]);
      bfr[jt][kt] = v;
    }
  }
  float bv[4];
#pragma unroll
  for (int jt = 0; jt < 4; jt++) bv[jt] = b[jt * 16 + r];
  int ntiles = (N + 15) >> 4;
  for (int tile = gw; tile < ntiles; tile += nwaves) {
    int n0 = tile * 16;
    int nodeA = n0 + r;
    const ushort_t* hrow = h + (size_t)((nodeA < N) ? nodeA : 0) * 128;
    bf16x8 afr[4];
#pragma unroll
    for (int kt = 0; kt < 4; kt++)
      afr[kt] = *(const bf16x8*)(hrow + kt * 32 + kg * 8);
    f32x4 acc[4];
#pragma unroll
    for (int jt = 0; jt < 4; jt++) acc[jt] = (f32x4){0.f, 0.f, 0.f, 0.f};
#pragma unroll
    for (int jt = 0; jt < 4; jt++)
#pragma unroll
      for (int kt = 0; kt < 4; kt++)
        acc[jt] = __builtin_amdgcn_mfma_f32_16x16x32_bf16(afr[kt], bfr[jt][kt], acc[jt], 0, 0, 0);
    // C layout: col j = jt*16 + (lane&15), row node = kg*4 + reg
#pragma unroll
    for (int jt = 0; jt < 4; jt++)
#pragma unroll
      for (int reg = 0; reg < 4; reg++) {
        int n = n0 + kg * 4 + reg;
        if (n < N) out[(size_t)n * 64 + jt * 16 + r] = acc[jt][reg] + bv[jt];
      }
  }
}

extern "C" void kernel_launch(void* const* d_in, const int* in_sizes, int n_in,
                              void* d_out, int out_size, void* d_ws, size_t ws_size,
                              hipStream_t stream) {
  const float* x_paper  = (const float*)d_in[0];
  const float* x_author = (const float*)d_in[1];
  const float* fc1p_W = (const float*)d_in[2];
  const float* fc1p_b = (const float*)d_in[3];
  const float* fc1a_W = (const float*)d_in[4];
  const float* fc1a_b = (const float*)d_in[5];
  const float* fc2_W  = (const float*)d_in[6];
  const float* fc2_b  = (const float*)d_in[7];
  const float* semW1  = (const float*)d_in[8];
  const float* semb1  = (const float*)d_in[9];
  const float* semw2  = (const float*)d_in[10];
  const float* d_pp = (const float*)d_in[11];
  const float* d_pa = (const float*)d_in[12];
  const float* d_ap = (const float*)d_in[13];
  const float* d_aa = (const float*)d_in[14];
  const float* w_pp = (const float*)d_in[15];
  const float* w_pa = (const float*)d_in[16];
  const float* w_ap = (const float*)d_in[17];
  const float* w_aa = (const float*)d_in[18];
  const int* src_pp = (const int*)d_in[19];
  const int* dst_pp = (const int*)d_in[20];
  const int* src_pa = (const int*)d_in[21];
  const int* dst_pa = (const int*)d_in[22];
  const int* src_ap = (const int*)d_in[23];
  const int* dst_ap = (const int*)d_in[24];
  const int* src_aa = (const int*)d_in[25];
  const int* dst_aa = (const int*)d_in[26];

  const int Np = in_sizes[11];
  const int Na = in_sizes[13];
  const int E[4] = { in_sizes[15], in_sizes[16], in_sizes[17], in_sizes[18] };
  const int Nmax = (Np > Na) ? Np : Na;

  char* base = (char*)d_ws;
  size_t off = 0;
  ushort_t* xp = (ushort_t*)(base + off); off += (size_t)Np * 128 * 2;
  ushort_t* xa = (ushort_t*)(base + off); off += (size_t)Na * 128 * 2;
  ushort_t* hp = (ushort_t*)(base + off); off += (size_t)Np * 128 * 2;
  ushort_t* ha = (ushort_t*)(base + off); off += (size_t)Na * 128 * 2;
  ushort_t* rel = (ushort_t*)(base + off); off += (size_t)Nmax * 256 * 2;
  float* ssum = (float*)(base + off); off += 32 * 4;
  int* cnt  = (int*)(base + off); off += (size_t)(2 * Np + 2 * Na) * 4;
  int* rpB  = (int*)(base + off); off += (size_t)(2 * (Np + 1) + 2 * (Na + 1)) * 4;
  int* curB = (int*)(base + off); off += (size_t)(2 * Np + 2 * Na) * 4;
  size_t Esum = (size_t)E[0] + E[1] + E[2] + E[3];
  int* colB = (int*)(base + off); off += Esum * 4;
  float* wB = (float*)(base + off); off += Esum * 4;
  (void)ws_size; (void)n_in; (void)out_size;

  int* cnt_r[4] = { cnt, cnt + Np, cnt + (size_t)2 * Np, cnt + (size_t)2 * Np + Na };
  int* rp_r[4]  = { rpB, rpB + (Np + 1), rpB + (size_t)2 * (Np + 1),
                    rpB + (size_t)2 * (Np + 1) + (Na + 1) };
  int* cur_r[4] = { curB, curB + Np, curB + (size_t)2 * Np, curB + (size_t)2 * Np + Na };
  size_t eoff[4] = { 0, (size_t)E[0], (size_t)E[0] + E[1], (size_t)E[0] + E[1] + E[2] };
  int* col_r[4]; float* w_r[4];
  for (int r = 0; r < 4; r++) { col_r[r] = colB + eoff[r]; w_r[r] = wB + eoff[r]; }

  const int* srcs[4]    = { src_pp, src_pa, src_ap, src_aa };
  const int* dsts[4]    = { dst_pp, dst_pa, dst_ap, dst_aa };
  const float* wedge[4] = { w_pp, w_pa, w_ap, w_aa };

  int Z = 32 + 2 * Np + 2 * Na;
  zero_kernel<<<(Z + 255) / 256, 256, 0, stream>>>(ssum, Z);

  for (int r = 0; r < 4; r++)
    hist_kernel<<<(E[r] + 255) / 256, 256, 0, stream>>>(dsts[r], E[r], cnt_r[r]);
  scan4_kernel<<<4, 1024, 0, stream>>>(cnt, rpB, curB, Np, Na);
  for (int r = 0; r < 4; r++)
    scatter_kernel<<<(E[r] + 255) / 256, 256, 0, stream>>>(srcs[r], dsts[r], wedge[r],
                                                           cur_r[r], col_r[r], w_r[r], E[r]);

  fc1_mfma_kernel<256, 2><<<256, 256, 0, stream>>>(x_paper, fc1p_W, fc1p_b, xp, hp, Np);
  fc1_mfma_kernel<128, 1><<<256, 256, 0, stream>>>(x_author, fc1a_W, fc1a_b, xa, ha, Na);

  const int SCORE_BLOCKS = 128;
  const int SCORE_WAVES = SCORE_BLOCKS * 4;

  for (int i = 0; i < 5; i++) {
    // paper: pp (gather h_p), pa (gather h_a)
    float* sp = ssum + (size_t)(i * 2 + 0) * 2;
    spmm2_kernel<<<(Np + 3) / 4, 256, 0, stream>>>(xp, d_pp, d_pa, hp, ha,
        rp_r[0], col_r[0], w_r[0], rp_r[1], col_r[1], w_r[1], rel, Np);
    score_mfma_kernel<<<SCORE_BLOCKS, 256, 0, stream>>>(rel,
        semW1 + (size_t)(i * 2 + 0) * 16384, semb1 + (size_t)(i * 2 + 0) * 128,
        semw2 + (size_t)(i * 2 + 0) * 128, sp, Np, SCORE_WAVES);
    combine_kernel<<<(Np * 16 + 255) / 256, 256, 0, stream>>>(rel, sp, hp, Np, 1.f / Np);

    // author: ap (gather new h_p), aa (gather h_a)
    float* sa = ssum + (size_t)(i * 2 + 1) * 2;
    spmm2_kernel<<<(Na + 3) / 4, 256, 0, stream>>>(xa, d_ap, d_aa, hp, ha,
        rp_r[2], col_r[2], w_r[2], rp_r[3], col_r[3], w_r[3], rel, Na);
    score_mfma_kernel<<<SCORE_BLOCKS, 256, 0, stream>>>(rel,
        semW1 + (size_t)(i * 2 + 1) * 16384, semb1 + (size_t)(i * 2 + 1) * 128,
        semw2 + (size_t)(i * 2 + 1) * 128, sa, Na, SCORE_WAVES);
    combine_kernel<<<(Na * 16 + 255) / 256, 256, 0, stream>>>(rel, sa, ha, Na, 1.f / Na);
  }

  fc2_mfma_kernel<<<256, 256, 0, stream>>>(hp, fc2_W, fc2_b, (float*)d_out, Np, 1024);
}

// Round 6
// 2877.052 us; speedup vs baseline: 2.9936x; 1.0513x over previous
//
#include <hip/hip_runtime.h>

// HetGTCN: 5-hop heterogeneous GNN on MI355X.
//   1. CSR build for 4 relations (hist -> shfl-scan -> scatter)
//   2. fc1p/fc1a: bf16 MFMA GEMM (W in registers, grid-strided node tiles)
//   3. 5 hops x 2 types: spmm2 (bf16 gather, 4-deep MLP unroll) -> score (bf16 MFMA)
//      -> combine (softmax beta blend)
//   4. fc2: bf16 MFMA (W2 in registers) -> d_out [Np,64] f32
// Round-5 lesson: spmm2 was latency-bound at MLP=2 outstanding gathers/wave;
// this version issues 4 (16 edges per wave-iteration, 4 per 16-lane slot).

typedef __attribute__((ext_vector_type(8))) short bf16x8;
typedef __attribute__((ext_vector_type(4))) float f32x4;
typedef unsigned short ushort_t;

__device__ inline unsigned short f2bf(float f) {
  union { float f; unsigned u; } x; x.f = f;
  unsigned r = x.u + 0x7fff + ((x.u >> 16) & 1);   // RNE
  return (unsigned short)(r >> 16);
}
__device__ inline float bf2f(unsigned short u) {
  union { unsigned u; float f; } x; x.u = (unsigned)u << 16; return x.f;
}
__device__ inline void unpack8(uint4 u, float* f) {
  union { unsigned u; float f; } c;
  c.u = u.x << 16;          f[0] = c.f;
  c.u = u.x & 0xffff0000u;  f[1] = c.f;
  c.u = u.y << 16;          f[2] = c.f;
  c.u = u.y & 0xffff0000u;  f[3] = c.f;
  c.u = u.z << 16;          f[4] = c.f;
  c.u = u.z & 0xffff0000u;  f[5] = c.f;
  c.u = u.w << 16;          f[6] = c.f;
  c.u = u.w & 0xffff0000u;  f[7] = c.f;
}
__device__ inline uint4 pack8(const float* f) {
  uint4 u;
  u.x = (unsigned)f2bf(f[0]) | ((unsigned)f2bf(f[1]) << 16);
  u.y = (unsigned)f2bf(f[2]) | ((unsigned)f2bf(f[3]) << 16);
  u.z = (unsigned)f2bf(f[4]) | ((unsigned)f2bf(f[5]) << 16);
  u.w = (unsigned)f2bf(f[6]) | ((unsigned)f2bf(f[7]) << 16);
  return u;
}

__global__ void zero_kernel(float* __restrict__ p, int n) {
  int i = blockIdx.x * blockDim.x + threadIdx.x;
  if (i < n) p[i] = 0.f;
}

__global__ void hist_kernel(const int* __restrict__ dst, int E, int* __restrict__ cnt) {
  int i = blockIdx.x * blockDim.x + threadIdx.x;
  if (i < E) atomicAdd(&cnt[dst[i]], 1);
}

// One block (1024 threads) per relation; shfl wave-scan, 3 barriers per 1024-chunk.
__global__ void scan4_kernel(const int* __restrict__ cnt, int* __restrict__ rp,
                             int* __restrict__ cur, int Np, int Na) {
  __shared__ int wsum[16];
  __shared__ int carry_s;
  int r = blockIdx.x;
  int N = (r < 2) ? Np : Na;
  size_t coff  = (r==0)?0 : (r==1)? (size_t)Np : (r==2)? (size_t)2*Np : (size_t)2*Np+Na;
  size_t rpoff = (r==0)?0 : (r==1)? (size_t)(Np+1) : (r==2)? (size_t)2*(Np+1) : (size_t)2*(Np+1)+(Na+1);
  const int* c = cnt + coff;
  int* rpp = rp + rpoff;
  int* cpp = cur + coff;
  int tid = threadIdx.x;
  int lane = tid & 63, wv = tid >> 6;
  if (tid == 0) carry_s = 0;
  for (int base = 0; base < N; base += 1024) {
    int i = base + tid;
    int v = (i < N) ? c[i] : 0;
    int s = v;
#pragma unroll
    for (int off = 1; off < 64; off <<= 1) {
      int t = __shfl_up(s, off);
      if (lane >= off) s += t;
    }
    if (lane == 63) wsum[wv] = s;
    __syncthreads();
    if (wv == 0 && lane < 16) {
      int p = wsum[lane];
      int q = p;
#pragma unroll
      for (int off = 1; off < 16; off <<= 1) {
        int t = __shfl_up(q, off);
        if (lane >= off) q += t;
      }
      wsum[lane] = q - p;   // exclusive wave prefix
    }
    __syncthreads();
    int carry = carry_s;
    int wexcl = wsum[wv];
    int excl = carry + wexcl + (s - v);
    if (i < N) { rpp[i] = excl; cpp[i] = excl; }
    int mytotal = wexcl + s;
    __syncthreads();
    if (tid == 1023) carry_s = carry + mytotal;
  }
  __syncthreads();
  if (tid == 0) rpp[N] = carry_s;
}

__global__ void scatter_kernel(const int* __restrict__ src, const int* __restrict__ dst,
                               const float* __restrict__ w, int* __restrict__ cur,
                               int* __restrict__ col, float* __restrict__ wout, int E) {
  int i = blockIdx.x * blockDim.x + threadIdx.x;
  if (i < E) {
    int p = atomicAdd(&cur[dst[i]], 1);
    col[p]  = src[i];
    wout[p] = w[i];
  }
}

// fc1 via bf16 MFMA: relu(x @ W + b) -> bf16 o1 (x table) and o2 (h table).
template<int K, int KH>
__global__ __launch_bounds__(256) void fc1_mfma_kernel(
    const float* __restrict__ x, const float* __restrict__ W,
    const float* __restrict__ b, ushort_t* __restrict__ o1, ushort_t* __restrict__ o2,
    int N) {
  constexpr int TPB = 4 / KH;
  __shared__ float cstage[4][16][128];   // 32 KB
  int tid = threadIdx.x;
  int lane = tid & 63, wid = tid >> 6;
  int tile = (KH == 2) ? (wid >> 1) : wid;
  int khalf = (KH == 2) ? (wid & 1) : 0;
  int r = lane & 15, kg = lane >> 4;
  bf16x8 bfr[8][4];
#pragma unroll
  for (int jt = 0; jt < 8; jt++) {
    int j = jt * 16 + r;
#pragma unroll
    for (int kt = 0; kt < 4; kt++) {
      int k0 = khalf * 128 + kt * 32 + kg * 8;
      bf16x8 v;
#pragma unroll
      for (int t = 0; t < 8; t++) v[t] = (short)f2bf(W[(size_t)(k0 + t) * 128 + j]);
      bfr[jt][kt] = v;
    }
  }
  float bb[8];
  {
    int j0 = (tid & 15) * 8;
#pragma unroll
    for (int t = 0; t < 8; t++) bb[t] = b[j0 + t];
  }
  int ntiles = (N + 15) >> 4;
  int tstride = gridDim.x * TPB;
  for (int tb = blockIdx.x * TPB; tb < ntiles; tb += tstride) {
    int mytile = tb + tile;
    int nodeA = mytile * 16 + r;
    if (nodeA >= N) nodeA = 0;
    const float* xrow = x + (size_t)nodeA * K + khalf * 128;
    bf16x8 afr[4];
#pragma unroll
    for (int kt = 0; kt < 4; kt++) {
      const float4* p = (const float4*)(xrow + kt * 32 + kg * 8);
      float4 lo = p[0], hi = p[1];
      bf16x8 v;
      v[0] = (short)f2bf(lo.x); v[1] = (short)f2bf(lo.y);
      v[2] = (short)f2bf(lo.z); v[3] = (short)f2bf(lo.w);
      v[4] = (short)f2bf(hi.x); v[5] = (short)f2bf(hi.y);
      v[6] = (short)f2bf(hi.z); v[7] = (short)f2bf(hi.w);
      afr[kt] = v;
    }
    f32x4 acc[8];
#pragma unroll
    for (int jt = 0; jt < 8; jt++) acc[jt] = (f32x4){0.f, 0.f, 0.f, 0.f};
#pragma unroll
    for (int jt = 0; jt < 8; jt++)
#pragma unroll
      for (int kt = 0; kt < 4; kt++)
        acc[jt] = __builtin_amdgcn_mfma_f32_16x16x32_bf16(afr[kt], bfr[jt][kt], acc[jt], 0, 0, 0);
#pragma unroll
    for (int jt = 0; jt < 8; jt++)
#pragma unroll
      for (int reg = 0; reg < 4; reg++)
        cstage[wid][kg * 4 + reg][jt * 16 + r] = acc[jt][reg];
    __syncthreads();
    int node = tid >> 4, j0 = (tid & 15) * 8;
#pragma unroll
    for (int it = 0; it < TPB; it++) {
      int n = (tb + it) * 16 + node;
      float f[8];
#pragma unroll
      for (int t = 0; t < 8; t++) {
        float v = cstage[it * KH][node][j0 + t];
        if (KH == 2) v += cstage[it * 2 + 1][node][j0 + t];
        f[t] = fmaxf(v + bb[t], 0.f);
      }
      if (n < N) {
        uint4 pk = pack8(f);
        *(uint4*)(o1 + (size_t)n * 128 + j0) = pk;
        *(uint4*)(o2 + (size_t)n * 128 + j0) = pk;
      }
    }
    __syncthreads();
  }
}

// Wave-per-node SPMM over 2 relations, bf16 rows (256B): 16 lanes x 16B per row.
// 16 edges per wave-iteration = 4 outstanding gathers per 16-lane slot (MLP=4).
__global__ __launch_bounds__(256) void spmm2_kernel(
    const ushort_t* __restrict__ xself,
    const float* __restrict__ d0, const float* __restrict__ d1,
    const ushort_t* __restrict__ h0, const ushort_t* __restrict__ h1,
    const int* __restrict__ rp0, const int* __restrict__ col0, const float* __restrict__ w0,
    const int* __restrict__ rp1, const int* __restrict__ col1, const float* __restrict__ w1,
    ushort_t* __restrict__ rel, int N) {
  int tid = threadIdx.x;
  int lane = tid & 63, wid = tid >> 6;
  int fg = lane & 15;
  int eslot = lane >> 4;
  int n = blockIdx.x * 4 + wid;
  if (n >= N) return;
  float xf[8];
  unpack8(*(const uint4*)(xself + (size_t)n * 128 + fg * 8), xf);
#pragma unroll
  for (int srel = 0; srel < 2; srel++) {
    const float sd = srel ? d1[n] : d0[n];
    const int* rp = srel ? rp1 : rp0;
    const int* col = srel ? col1 : col0;
    const float* wv_arr = srel ? w1 : w0;
    const ushort_t* h = srel ? h1 : h0;
    float acc[8];
#pragma unroll
    for (int t = 0; t < 8; t++) acc[t] = 0.f;
    int beg = rp[n], end = rp[n + 1];
    for (int cb = beg; cb < end; cb += 64) {
      int m = end - cb; if (m > 64) m = 64;
      int creg = 0; float wreg = 0.f;
      if (lane < m) { creg = col[cb + lane]; wreg = wv_arr[cb + lane]; }
      int i = 0;
      // main: 16 edges per iteration, 4 gathers in flight per 16-lane slot
      for (; i + 16 <= m; i += 16) {
        int e0 = i + eslot, e1 = i + 4 + eslot, e2 = i + 8 + eslot, e3 = i + 12 + eslot;
        int   c0 = __shfl(creg, e0), c1 = __shfl(creg, e1);
        int   c2 = __shfl(creg, e2), c3 = __shfl(creg, e3);
        float v0 = __shfl(wreg, e0), v1 = __shfl(wreg, e1);
        float v2 = __shfl(wreg, e2), v3 = __shfl(wreg, e3);
        uint4 g0 = *(const uint4*)(h + (size_t)c0 * 128 + fg * 8);
        uint4 g1 = *(const uint4*)(h + (size_t)c1 * 128 + fg * 8);
        uint4 g2 = *(const uint4*)(h + (size_t)c2 * 128 + fg * 8);
        uint4 g3 = *(const uint4*)(h + (size_t)c3 * 128 + fg * 8);
        float hf[8];
        unpack8(g0, hf);
#pragma unroll
        for (int t = 0; t < 8; t++) acc[t] = fmaf(v0, hf[t], acc[t]);
        unpack8(g1, hf);
#pragma unroll
        for (int t = 0; t < 8; t++) acc[t] = fmaf(v1, hf[t], acc[t]);
        unpack8(g2, hf);
#pragma unroll
        for (int t = 0; t < 8; t++) acc[t] = fmaf(v2, hf[t], acc[t]);
        unpack8(g3, hf);
#pragma unroll
        for (int t = 0; t < 8; t++) acc[t] = fmaf(v3, hf[t], acc[t]);
      }
      // tail: 4 edges per iteration, masked
      for (; i < m; i += 4) {
        int e = i + eslot;
        int   c = __shfl(creg, e & 63);
        float v = __shfl(wreg, e & 63);
        if (e < m) {
          uint4 g = *(const uint4*)(h + (size_t)c * 128 + fg * 8);
          float hf[8];
          unpack8(g, hf);
#pragma unroll
          for (int t = 0; t < 8; t++) acc[t] = fmaf(v, hf[t], acc[t]);
        }
      }
    }
#pragma unroll
    for (int t = 0; t < 8; t++) {
      acc[t] += __shfl_xor(acc[t], 16);
      acc[t] += __shfl_xor(acc[t], 32);
    }
    if (eslot == 0) {
#pragma unroll
      for (int t = 0; t < 8; t++) acc[t] = fmaf(sd, xf[t], acc[t]);
      *(uint4*)(rel + (size_t)n * 256 + srel * 128 + fg * 8) = pack8(acc);
    }
  }
}

// HAN scores via bf16 MFMA. W1 held in registers as B-frags; A-frags direct bf16 loads.
__global__ __launch_bounds__(256) void score_mfma_kernel(
    const ushort_t* __restrict__ rel,   // [N,2,128] bf16
    const float* __restrict__ W1,       // [128,128] (k-major)
    const float* __restrict__ b1, const float* __restrict__ w2,
    float* __restrict__ s_out, int N, int nwaves) {
  int tid = threadIdx.x;
  int lane = tid & 63;
  int gw = blockIdx.x * 4 + (tid >> 6);
  int r = lane & 15;
  int kg = lane >> 4;
  bf16x8 bfr[8][4];
#pragma unroll
  for (int jt = 0; jt < 8; jt++) {
    int j = jt * 16 + r;
#pragma unroll
    for (int kt = 0; kt < 4; kt++) {
      int k0 = kt * 32 + kg * 8;
      bf16x8 v;
#pragma unroll
      for (int t = 0; t < 8; t++) v[t] = (short)f2bf(W1[(size_t)(k0 + t) * 128 + j]);
      bfr[jt][kt] = v;
    }
  }
  float b1v[8], w2v[8];
#pragma unroll
  for (int jt = 0; jt < 8; jt++) { b1v[jt] = b1[jt * 16 + r]; w2v[jt] = w2[jt * 16 + r]; }
  float s0 = 0.f, s1 = 0.f;
  int ntiles = (N + 15) >> 4;
  for (int tile = gw; tile < ntiles; tile += nwaves) {
    int n0 = tile * 16;
    int nodeA = n0 + r;
    size_t base = (size_t)((nodeA < N) ? nodeA : 0) * 256;
#pragma unroll
    for (int sub = 0; sub < 2; sub++) {
      bf16x8 afr[4];
#pragma unroll
      for (int kt = 0; kt < 4; kt++)
        afr[kt] = *(const bf16x8*)(rel + base + sub * 128 + kt * 32 + kg * 8);
      f32x4 acc[8];
#pragma unroll
      for (int jt = 0; jt < 8; jt++) acc[jt] = (f32x4){0.f, 0.f, 0.f, 0.f};
#pragma unroll
      for (int jt = 0; jt < 8; jt++)
#pragma unroll
        for (int kt = 0; kt < 4; kt++)
          acc[jt] = __builtin_amdgcn_mfma_f32_16x16x32_bf16(afr[kt], bfr[jt][kt], acc[jt], 0, 0, 0);
      float sacc = 0.f;
#pragma unroll
      for (int jt = 0; jt < 8; jt++) {
#pragma unroll
        for (int reg = 0; reg < 4; reg++) {
          int nm = n0 + kg * 4 + reg;
          if (nm < N) sacc += w2v[jt] * tanhf(acc[jt][reg] + b1v[jt]);
        }
      }
      if (sub == 0) s0 += sacc; else s1 += sacc;
    }
  }
#pragma unroll
  for (int m = 32; m >= 1; m >>= 1) { s0 += __shfl_xor(s0, m); s1 += __shfl_xor(s1, m); }
  if (lane == 0) { atomicAdd(&s_out[0], s0); atomicAdd(&s_out[1], s1); }
}

// h[n,:] = beta0*rel[n,0,:] + beta1*rel[n,1,:]; bf16 in/out, 8 feats/thread.
__global__ void combine_kernel(const ushort_t* __restrict__ rel, const float* __restrict__ s,
                               ushort_t* __restrict__ h, int N, float invN) {
  int i = blockIdx.x * blockDim.x + threadIdx.x;
  if (i >= N * 16) return;
  float m0 = s[0] * invN, m1 = s[1] * invN;
  float mx = fmaxf(m0, m1);
  float e0 = expf(m0 - mx), e1 = expf(m1 - mx);
  float inv = 1.f / (e0 + e1);
  float be0 = e0 * inv, be1 = e1 * inv;
  int n = i >> 4, q = i & 15;
  float f0[8], f1[8], o[8];
  unpack8(*(const uint4*)(rel + (size_t)n * 256 + q * 8), f0);
  unpack8(*(const uint4*)(rel + (size_t)n * 256 + 128 + q * 8), f1);
#pragma unroll
  for (int t = 0; t < 8; t++) o[t] = be0 * f0[t] + be1 * f1[t];
  *(uint4*)(h + (size_t)n * 128 + q * 8) = pack8(o);
}

// fc2 via bf16 MFMA: out = h @ W2(128x64) + b2. Wave = 16-node tile, grid-strided;
// W2 as B-frags in registers (4 j-tiles x 4 k-tiles), A-frags direct bf16 h loads.
__global__ __launch_bounds__(256) void fc2_mfma_kernel(
    const ushort_t* __restrict__ h,     // [N,128] bf16
    const float* __restrict__ W,        // [128,64]
    const float* __restrict__ b,        // [64]
    float* __restrict__ out, int N, int nwaves) {
  int tid = threadIdx.x;
  int lane = tid & 63;
  int gw = blockIdx.x * 4 + (tid >> 6);
  int r = lane & 15, kg = lane >> 4;
  bf16x8 bfr[4][4];
#pragma unroll
  for (int jt = 0; jt < 4; jt++) {
    int j = jt * 16 + r;
#pragma unroll
    for (int kt = 0; kt < 4; kt++) {
      int k0 = kt * 32 + kg * 8;
      bf16x8 v;
#pragma unroll
      for (int t = 0; t < 8; t++) v[t] = (short)f2bf(W[(size_t)(k0 + t) * 64 + j]);
      bfr[jt][kt] = v;
    }
  }
  float bv[4];
#pragma unroll
  for (int jt = 0; jt < 4; jt++) bv[jt] = b[jt * 16 + r];
  int ntiles = (N + 15) >> 4;
  for (int tile = gw; tile < ntiles; tile += nwaves) {
    int n0 = tile * 16;
    int nodeA = n0 + r;
    const ushort_t* hrow = h + (size_t)((nodeA < N) ? nodeA : 0) * 128;
    bf16x8 afr[4];
#pragma unroll
    for (int kt = 0; kt < 4; kt++)
      afr[kt] = *(const bf16x8*)(hrow + kt * 32 + kg * 8);
    f32x4 acc[4];
#pragma unroll
    for (int jt = 0; jt < 4; jt++) acc[jt] = (f32x4){0.f, 0.f, 0.f, 0.f};
#pragma unroll
    for (int jt = 0; jt < 4; jt++)
#pragma unroll
      for (int kt = 0; kt < 4; kt++)
        acc[jt] = __builtin_amdgcn_mfma_f32_16x16x32_bf16(afr[kt], bfr[jt][kt], acc[jt], 0, 0, 0);
#pragma unroll
    for (int jt = 0; jt < 4; jt++)
#pragma unroll
      for (int reg = 0; reg < 4; reg++) {
        int n = n0 + kg * 4 + reg;
        if (n < N) out[(size_t)n * 64 + jt * 16 + r] = acc[jt][reg] + bv[jt];
      }
  }
}

extern "C" void kernel_launch(void* const* d_in, const int* in_sizes, int n_in,
                              void* d_out, int out_size, void* d_ws, size_t ws_size,
                              hipStream_t stream) {
  const float* x_paper  = (const float*)d_in[0];
  const float* x_author = (const float*)d_in[1];
  const float* fc1p_W = (const float*)d_in[2];
  const float* fc1p_b = (const float*)d_in[3];
  const float* fc1a_W = (const float*)d_in[4];
  const float* fc1a_b = (const float*)d_in[5];
  const float* fc2_W  = (const float*)d_in[6];
  const float* fc2_b  = (const float*)d_in[7];
  const float* semW1  = (const float*)d_in[8];
  const float* semb1  = (const float*)d_in[9];
  const float* semw2  = (const float*)d_in[10];
  const float* d_pp = (const float*)d_in[11];
  const float* d_pa = (const float*)d_in[12];
  const float* d_ap = (const float*)d_in[13];
  const float* d_aa = (const float*)d_in[14];
  const float* w_pp = (const float*)d_in[15];
  const float* w_pa = (const float*)d_in[16];
  const float* w_ap = (const float*)d_in[17];
  const float* w_aa = (const float*)d_in[18];
  const int* src_pp = (const int*)d_in[19];
  const int* dst_pp = (const int*)d_in[20];
  const int* src_pa = (const int*)d_in[21];
  const int* dst_pa = (const int*)d_in[22];
  const int* src_ap = (const int*)d_in[23];
  const int* dst_ap = (const int*)d_in[24];
  const int* src_aa = (const int*)d_in[25];
  const int* dst_aa = (const int*)d_in[26];

  const int Np = in_sizes[11];
  const int Na = in_sizes[13];
  const int E[4] = { in_sizes[15], in_sizes[16], in_sizes[17], in_sizes[18] };
  const int Nmax = (Np > Na) ? Np : Na;

  char* base = (char*)d_ws;
  size_t off = 0;
  ushort_t* xp = (ushort_t*)(base + off); off += (size_t)Np * 128 * 2;
  ushort_t* xa = (ushort_t*)(base + off); off += (size_t)Na * 128 * 2;
  ushort_t* hp = (ushort_t*)(base + off); off += (size_t)Np * 128 * 2;
  ushort_t* ha = (ushort_t*)(base + off); off += (size_t)Na * 128 * 2;
  ushort_t* rel = (ushort_t*)(base + off); off += (size_t)Nmax * 256 * 2;
  float* ssum = (float*)(base + off); off += 32 * 4;
  int* cnt  = (int*)(base + off); off += (size_t)(2 * Np + 2 * Na) * 4;
  int* rpB  = (int*)(base + off); off += (size_t)(2 * (Np + 1) + 2 * (Na + 1)) * 4;
  int* curB = (int*)(base + off); off += (size_t)(2 * Np + 2 * Na) * 4;
  size_t Esum = (size_t)E[0] + E[1] + E[2] + E[3];
  int* colB = (int*)(base + off); off += Esum * 4;
  float* wB = (float*)(base + off); off += Esum * 4;
  (void)ws_size; (void)n_in; (void)out_size;

  int* cnt_r[4] = { cnt, cnt + Np, cnt + (size_t)2 * Np, cnt + (size_t)2 * Np + Na };
  int* rp_r[4]  = { rpB, rpB + (Np + 1), rpB + (size_t)2 * (Np + 1),
                    rpB + (size_t)2 * (Np + 1) + (Na + 1) };
  int* cur_r[4] = { curB, curB + Np, curB + (size_t)2 * Np, curB + (size_t)2 * Np + Na };
  size_t eoff[4] = { 0, (size_t)E[0], (size_t)E[0] + E[1], (size_t)E[0] + E[1] + E[2] };
  int* col_r[4]; float* w_r[4];
  for (int r = 0; r < 4; r++) { col_r[r] = colB + eoff[r]; w_r[r] = wB + eoff[r]; }

  const int* srcs[4]    = { src_pp, src_pa, src_ap, src_aa };
  const int* dsts[4]    = { dst_pp, dst_pa, dst_ap, dst_aa };
  const float* wedge[4] = { w_pp, w_pa, w_ap, w_aa };

  int Z = 32 + 2 * Np + 2 * Na;
  zero_kernel<<<(Z + 255) / 256, 256, 0, stream>>>(ssum, Z);

  for (int r = 0; r < 4; r++)
    hist_kernel<<<(E[r] + 255) / 256, 256, 0, stream>>>(dsts[r], E[r], cnt_r[r]);
  scan4_kernel<<<4, 1024, 0, stream>>>(cnt, rpB, curB, Np, Na);
  for (int r = 0; r < 4; r++)
    scatter_kernel<<<(E[r] + 255) / 256, 256, 0, stream>>>(srcs[r], dsts[r], wedge[r],
                                                           cur_r[r], col_r[r], w_r[r], E[r]);

  fc1_mfma_kernel<256, 2><<<256, 256, 0, stream>>>(x_paper, fc1p_W, fc1p_b, xp, hp, Np);
  fc1_mfma_kernel<128, 1><<<256, 256, 0, stream>>>(x_author, fc1a_W, fc1a_b, xa, ha, Na);

  const int SCORE_BLOCKS = 256;
  const int SCORE_WAVES = SCORE_BLOCKS * 4;

  for (int i = 0; i < 5; i++) {
    // paper: pp (gather h_p), pa (gather h_a)
    float* sp = ssum + (size_t)(i * 2 + 0) * 2;
    spmm2_kernel<<<(Np + 3) / 4, 256, 0, stream>>>(xp, d_pp, d_pa, hp, ha,
        rp_r[0], col_r[0], w_r[0], rp_r[1], col_r[1], w_r[1], rel, Np);
    score_mfma_kernel<<<SCORE_BLOCKS, 256, 0, stream>>>(rel,
        semW1 + (size_t)(i * 2 + 0) * 16384, semb1 + (size_t)(i * 2 + 0) * 128,
        semw2 + (size_t)(i * 2 + 0) * 128, sp, Np, SCORE_WAVES);
    combine_kernel<<<(Np * 16 + 255) / 256, 256, 0, stream>>>(rel, sp, hp, Np, 1.f / Np);

    // author: ap (gather new h_p), aa (gather h_a)
    float* sa = ssum + (size_t)(i * 2 + 1) * 2;
    spmm2_kernel<<<(Na + 3) / 4, 256, 0, stream>>>(xa, d_ap, d_aa, hp, ha,
        rp_r[2], col_r[2], w_r[2], rp_r[3], col_r[3], w_r[3], rel, Na);
    score_mfma_kernel<<<SCORE_BLOCKS, 256, 0, stream>>>(rel,
        semW1 + (size_t)(i * 2 + 1) * 16384, semb1 + (size_t)(i * 2 + 1) * 128,
        semw2 + (size_t)(i * 2 + 1) * 128, sa, Na, SCORE_WAVES);
    combine_kernel<<<(Na * 16 + 255) / 256, 256, 0, stream>>>(rel, sa, ha, Na, 1.f / Na);
  }

  fc2_mfma_kernel<<<256, 256, 0, stream>>>(hp, fc2_W, fc2_b, (float*)d_out, Np, 1024);
}